// Round 1
// baseline (10541.705 us; speedup 1.0000x reference)
//
#include <hip/hip_runtime.h>
#include <math.h>

// eval-mode BatchNorm3d scale: np.float32(1/sqrt(1+1e-5))
#define BN_S 0.9999950000374997f

__device__ __forceinline__ float silu_f(float x) {
    return __fdividef(x, 1.0f + __expf(-x));
}

// ---------------------------------------------------------------------------
// Prep: W_em = ew2 @ mw1[64:], W_mu = mw2 @ uw1, b_mu = mb2 @ uw1 + ub1
// grid(64), block(64)
// ---------------------------------------------------------------------------
__global__ __launch_bounds__(64) void prep_w_k(
    const float* __restrict__ ew2, const float* __restrict__ mw1,
    const float* __restrict__ mw2, const float* __restrict__ uw1,
    const float* __restrict__ mb2, const float* __restrict__ ub1,
    float* __restrict__ W_em, float* __restrict__ W_mu, float* __restrict__ b_mu)
{
    const int k = blockIdx.x, c = threadIdx.x;
    float s = 0.f;
    for (int m = 0; m < 64; m++) s = fmaf(ew2[k*64 + m], mw1[(64 + m)*64 + c], s);
    W_em[k*64 + c] = s;
    float s2 = 0.f;
    for (int m = 0; m < 64; m++) s2 = fmaf(mw2[k*64 + m], uw1[m*64 + c], s2);
    W_mu[k*64 + c] = s2;
    if (k == 0) {
        float s3 = ub1[c];
        for (int m = 0; m < 64; m++) s3 = fmaf(mb2[m], uw1[m*64 + c], s3);
        b_mu[c] = s3;
    }
}

// ---------------------------------------------------------------------------
// Prep per-node / per-voxel tables.
// a_node[v][c] = node_pos[v] @ ew1[0:3] + eb1      (edge-MLP L1, node part)
// g_vox [v][c] = grid_pos[v] @ ew1[3:6]            (edge-MLP L1, grid part)
// n_node[v][c] = node_emb[v] @ mw1[:64] + mb1 + eb2 @ mw1[64:]
// grid(4096), block(64)
// ---------------------------------------------------------------------------
__global__ __launch_bounds__(64) void prep_nodes_k(
    const float* __restrict__ node_embedding, const float* __restrict__ node_pos,
    const float* __restrict__ grid_pos, const float* __restrict__ ew1,
    const float* __restrict__ eb1, const float* __restrict__ mw1,
    const float* __restrict__ mb1, const float* __restrict__ eb2,
    float* __restrict__ a_node, float* __restrict__ g_vox, float* __restrict__ n_node)
{
    const int v = blockIdx.x, c = threadIdx.x;
    const float p0 = node_pos[v*3], p1 = node_pos[v*3 + 1], p2 = node_pos[v*3 + 2];
    a_node[v*64 + c] = fmaf(p0, ew1[c], fmaf(p1, ew1[64 + c], fmaf(p2, ew1[128 + c], eb1[c])));
    const float q0 = grid_pos[v*3], q1 = grid_pos[v*3 + 1], q2 = grid_pos[v*3 + 2];
    g_vox[v*64 + c] = fmaf(q0, ew1[192 + c], fmaf(q1, ew1[256 + c], q2 * ew1[320 + c]));
    float s = mb1[c];
    for (int k = 0; k < 64; k++) s = fmaf(node_embedding[v*64 + k], mw1[k*64 + c], s);
    for (int k = 0; k < 64; k++) s = fmaf(eb2[k], mw1[(64 + k)*64 + c], s);
    n_node[v*64 + c] = s;
}

// ---------------------------------------------------------------------------
// Edge kernel: one block per grid voxel j (edges j*256..j*256+255 contiguous).
// Per tile of 64 edges:
//   Phase A: S1[r][c] = silu(a_node[i_r][c] + g_vox[j][c])  -> LDS
//   Phase B: H = S1 @ W_em + n_node[i]; psum += silu(H)   (4x4 micro-tiles)
// Tail: mean -> t1 = silu(mean @ W_mu + b_mu); gf = t1 @ uw2 + ub2;
//       x0[c][j] = gf * BN
// grid(4096), block(256)
// ---------------------------------------------------------------------------
__global__ __launch_bounds__(256) void edge_kernel(
    const int* __restrict__ edge_i,
    const float* __restrict__ a_node, const float* __restrict__ g_vox,
    const float* __restrict__ n_node, const float* __restrict__ W_em,
    const float* __restrict__ W_mu, const float* __restrict__ b_mu,
    const float* __restrict__ uw2, const float* __restrict__ ub2,
    float* __restrict__ x0)
{
    __shared__ float sW[64*64];       // W_em
    __shared__ float sS1[64*68];      // S1 tile, stride 68 (b128-aligned, low conflict)
    __shared__ float sRed[16*64];
    __shared__ float sV1[64];
    __shared__ float sV2[64];

    const int j = blockIdx.x;
    const int t = threadIdx.x;

    {   // stage W_em (1024 float4)
        const float4* src = (const float4*)W_em;
        float4* dst = (float4*)sW;
        #pragma unroll
        for (int q = 0; q < 4; q++) dst[t + 256*q] = src[t + 256*q];
    }

    const int tr = t >> 4, tc = t & 15;
    const int ebase = j << 8;
    const float* gj = g_vox + j*64;
    float psum[4] = {0.f, 0.f, 0.f, 0.f};

    for (int T = 0; T < 4; T++) {
        __syncthreads();   // prev tile consumed (also covers sW staging on T=0)
        {   // Phase A: r = t>>2 (64 rows), 16 channels each
            const int r = t >> 2, sub = t & 3;
            const int i = edge_i[ebase + T*64 + r];
            const float4* ai = (const float4*)(a_node + i*64 + sub*16);
            const float4* gi = (const float4*)(gj + sub*16);
            float4* dst = (float4*)(sS1 + r*68 + sub*16);
            #pragma unroll
            for (int q = 0; q < 4; q++) {
                float4 a = ai[q], g = gi[q], o;
                o.x = silu_f(a.x + g.x); o.y = silu_f(a.y + g.y);
                o.z = silu_f(a.z + g.z); o.w = silu_f(a.w + g.w);
                dst[q] = o;
            }
        }
        __syncthreads();
        // Phase B: thread (tr,tc) owns rows 4tr..4tr+3, cols 4tc..4tc+3
        float acc[4][4];
        #pragma unroll
        for (int ri = 0; ri < 4; ri++) {
            const int i = edge_i[ebase + T*64 + tr*4 + ri];
            const float4 nv = *(const float4*)(n_node + i*64 + tc*4);
            acc[ri][0] = nv.x; acc[ri][1] = nv.y; acc[ri][2] = nv.z; acc[ri][3] = nv.w;
        }
        #pragma unroll
        for (int k = 0; k < 64; k += 4) {
            float sva[4][4], wva[4][4];
            #pragma unroll
            for (int ri = 0; ri < 4; ri++) {
                const float4 v = *(const float4*)(sS1 + (tr*4 + ri)*68 + k);
                sva[ri][0] = v.x; sva[ri][1] = v.y; sva[ri][2] = v.z; sva[ri][3] = v.w;
            }
            #pragma unroll
            for (int kk = 0; kk < 4; kk++) {
                const float4 v = *(const float4*)(sW + (k + kk)*64 + tc*4);
                wva[kk][0] = v.x; wva[kk][1] = v.y; wva[kk][2] = v.z; wva[kk][3] = v.w;
            }
            #pragma unroll
            for (int ri = 0; ri < 4; ri++)
                #pragma unroll
                for (int kk = 0; kk < 4; kk++)
                    #pragma unroll
                    for (int ci = 0; ci < 4; ci++)
                        acc[ri][ci] = fmaf(sva[ri][kk], wva[kk][ci], acc[ri][ci]);
        }
        #pragma unroll
        for (int ri = 0; ri < 4; ri++)
            #pragma unroll
            for (int ci = 0; ci < 4; ci++)
                psum[ci] += silu_f(acc[ri][ci]);
    }

    __syncthreads();
    *(float4*)(sRed + tr*64 + tc*4) = *(float4*)psum;
    __syncthreads();
    if (t < 64) {
        float s = 0.f;
        #pragma unroll
        for (int q = 0; q < 16; q++) s += sRed[q*64 + t];
        sV1[t] = s * (1.0f / 256.0f);
    }
    __syncthreads();
    if (t < 64) {
        float h = b_mu[t];
        for (int k = 0; k < 64; k++) h = fmaf(sV1[k], W_mu[k*64 + t], h);
        sV2[t] = silu_f(h);
    }
    __syncthreads();
    if (t < 64) {
        float g = ub2[t];
        for (int k = 0; k < 64; k++) g = fmaf(sV2[k], uw2[k*64 + t], g);
        x0[t*4096 + j] = g * BN_S;   // transpose + instance-norm scale folded in
    }
}

// ---------------------------------------------------------------------------
// Conv3D, NCDHW, 16^3, zero pad. One block = one d-plane (16x16 threads),
// COT output channels per thread. K slices of the current input channel in LDS.
// MODE 0: out = relu(conv*BN)   (conv a)
// MODE 1: out = conv*BN         (conv b, stored for the add)
// MODE 2: out = relu(conv*BN + addsrc)  (conv shortcut + residual add)
// grid(16, CO/COT), block(256)
// ---------------------------------------------------------------------------
template<int K, int CI, int COT, int MODE>
__global__ __launch_bounds__(256) void conv3d_k(
    const float* __restrict__ in, const float* __restrict__ wt,
    const float* __restrict__ addsrc, float* __restrict__ out)
{
    constexpr int P = K / 2;
    __shared__ float sl[K][256];
    const int d0 = blockIdx.x;
    const int cog = blockIdx.y;
    const int t = threadIdx.x;
    const int h = t >> 4, w = t & 15;

    float acc[COT];
    #pragma unroll
    for (int c = 0; c < COT; c++) acc[c] = 0.f;

    for (int ci = 0; ci < CI; ci++) {
        __syncthreads();
        #pragma unroll
        for (int kd = 0; kd < K; kd++) {
            const int z = d0 + kd - P;
            sl[kd][t] = ((unsigned)z < 16u) ? in[(ci*16 + z)*256 + t] : 0.f;
        }
        __syncthreads();
        #pragma unroll
        for (int kd = 0; kd < K; kd++) {
            float vals[K*K];
            #pragma unroll
            for (int kh = 0; kh < K; kh++) {
                #pragma unroll
                for (int kw = 0; kw < K; kw++) {
                    const int hh = h + kh - P, ww = w + kw - P;
                    const bool ok = ((unsigned)hh < 16u) && ((unsigned)ww < 16u);
                    const int idx = ok ? (hh*16 + ww) : 0;
                    vals[kh*K + kw] = ok ? sl[kd][idx] : 0.f;
                }
            }
            #pragma unroll
            for (int c = 0; c < COT; c++) {
                const float* wp = wt + (((cog*COT + c)*CI + ci)*K + kd)*(K*K);
                #pragma unroll
                for (int q = 0; q < K*K; q++) acc[c] = fmaf(vals[q], wp[q], acc[c]);
            }
        }
    }
    const int vox = d0*256 + t;
    #pragma unroll
    for (int c = 0; c < COT; c++) {
        float v = acc[c] * BN_S;
        const int o = (cog*COT + c)*4096 + vox;
        if (MODE == 0) v = fmaxf(v, 0.f);
        if (MODE == 2) v = fmaxf(v + addsrc[o], 0.f);
        out[o] = v;
    }
}

// ---------------------------------------------------------------------------
// Max-pool over spatial (4096) per channel. grid(256), block(256)
// ---------------------------------------------------------------------------
__global__ __launch_bounds__(256) void maxpool_k(
    const float* __restrict__ x, float* __restrict__ pooled)
{
    const int c = blockIdx.x;
    float m = -3.4e38f;
    for (int v = threadIdx.x; v < 4096; v += 256) m = fmaxf(m, x[c*4096 + v]);
    #pragma unroll
    for (int off = 32; off > 0; off >>= 1) m = fmaxf(m, __shfl_down(m, off, 64));
    __shared__ float sm[4];
    if ((threadIdx.x & 63) == 0) sm[threadIdx.x >> 6] = m;
    __syncthreads();
    if (threadIdx.x == 0)
        pooled[c] = fmaxf(fmaxf(sm[0], sm[1]), fmaxf(sm[2], sm[3]));
}

// ---------------------------------------------------------------------------
// Final FC: out[n] = pooled @ fcw + fcb. grid(1), block(64)
// ---------------------------------------------------------------------------
__global__ __launch_bounds__(64) void fc_k(
    const float* __restrict__ pooled, const float* __restrict__ fcw,
    const float* __restrict__ fcb, float* __restrict__ out)
{
    __shared__ float sp[256];
    const int t = threadIdx.x;
    for (int q = t; q < 256; q += 64) sp[q] = pooled[q];
    __syncthreads();
    if (t < 20) {
        float s = fcb[t];
        for (int c = 0; c < 256; c++) s = fmaf(sp[c], fcw[c*20 + t], s);
        out[t] = s;
    }
}

// ---------------------------------------------------------------------------
extern "C" void kernel_launch(void* const* d_in, const int* in_sizes, int n_in,
                              void* d_out, int out_size, void* d_ws, size_t ws_size,
                              hipStream_t stream)
{
    const float* node_embedding = (const float*)d_in[0];
    const float* node_pos       = (const float*)d_in[1];
    const float* grid_pos       = (const float*)d_in[2];
    const int*   edge_index     = (const int*)d_in[3];
    const float* ew1 = (const float*)d_in[4];
    const float* eb1 = (const float*)d_in[5];
    const float* ew2 = (const float*)d_in[6];
    const float* eb2 = (const float*)d_in[7];
    const float* mw1 = (const float*)d_in[8];
    const float* mb1 = (const float*)d_in[9];
    const float* mw2 = (const float*)d_in[10];
    const float* mb2 = (const float*)d_in[11];
    const float* uw1 = (const float*)d_in[12];
    const float* ub1 = (const float*)d_in[13];
    const float* uw2 = (const float*)d_in[14];
    const float* ub2 = (const float*)d_in[15];
    const float* c1a = (const float*)d_in[16];
    const float* c1b = (const float*)d_in[17];
    const float* c1s = (const float*)d_in[18];
    const float* c2a = (const float*)d_in[19];
    const float* c2b = (const float*)d_in[20];
    const float* c2s = (const float*)d_in[21];
    const float* c3a = (const float*)d_in[22];
    const float* c3b = (const float*)d_in[23];
    const float* c3s = (const float*)d_in[24];
    const float* fcw = (const float*)d_in[25];
    const float* fcb = (const float*)d_in[26];
    float* out = (float*)d_out;
    const int* edge_i = edge_index;   // row 0; row 1 (edge_j) == repeat(arange(4096),256)

    float* ws = (float*)d_ws;
    float* a_node = ws; ws += 4096*64;
    float* g_vox  = ws; ws += 4096*64;
    float* n_node = ws; ws += 4096*64;
    float* W_em   = ws; ws += 64*64;
    float* W_mu   = ws; ws += 64*64;
    float* b_mu   = ws; ws += 64;
    float* x0 = ws; ws += 64*4096;
    float* t1 = ws; ws += 64*4096;
    float* u1 = ws; ws += 64*4096;
    float* x1 = ws; ws += 64*4096;
    float* t2 = ws; ws += 128*4096;
    float* u2 = ws; ws += 128*4096;
    float* x2 = ws; ws += 128*4096;
    float* t3 = ws; ws += 256*4096;
    float* u3 = ws; ws += 256*4096;
    float* x3 = ws; ws += 256*4096;
    float* pooled = ws; ws += 256;

    hipLaunchKernelGGL(prep_w_k, dim3(64), dim3(64), 0, stream,
                       ew2, mw1, mw2, uw1, mb2, ub1, W_em, W_mu, b_mu);
    hipLaunchKernelGGL(prep_nodes_k, dim3(4096), dim3(64), 0, stream,
                       node_embedding, node_pos, grid_pos, ew1, eb1, mw1, mb1, eb2,
                       a_node, g_vox, n_node);
    hipLaunchKernelGGL(edge_kernel, dim3(4096), dim3(256), 0, stream,
                       edge_i, a_node, g_vox, n_node, W_em, W_mu, b_mu, uw2, ub2, x0);

    // Block 1: 64 -> 64
    hipLaunchKernelGGL((conv3d_k<3,64,4,0>),  dim3(16,16), dim3(256), 0, stream, x0, c1a, nullptr, t1);
    hipLaunchKernelGGL((conv3d_k<3,64,4,1>),  dim3(16,16), dim3(256), 0, stream, t1, c1b, nullptr, u1);
    hipLaunchKernelGGL((conv3d_k<5,64,4,2>),  dim3(16,16), dim3(256), 0, stream, x0, c1s, u1, x1);
    // Block 2: 64 -> 128
    hipLaunchKernelGGL((conv3d_k<3,64,8,0>),  dim3(16,16), dim3(256), 0, stream, x1, c2a, nullptr, t2);
    hipLaunchKernelGGL((conv3d_k<3,128,8,1>), dim3(16,16), dim3(256), 0, stream, t2, c2b, nullptr, u2);
    hipLaunchKernelGGL((conv3d_k<5,64,8,2>),  dim3(16,16), dim3(256), 0, stream, x1, c2s, u2, x2);
    // Block 3: 128 -> 256
    hipLaunchKernelGGL((conv3d_k<3,128,8,0>), dim3(16,32), dim3(256), 0, stream, x2, c3a, nullptr, t3);
    hipLaunchKernelGGL((conv3d_k<3,256,8,1>), dim3(16,32), dim3(256), 0, stream, t3, c3b, nullptr, u3);
    hipLaunchKernelGGL((conv3d_k<5,128,8,2>), dim3(16,32), dim3(256), 0, stream, x2, c3s, u3, x3);

    hipLaunchKernelGGL(maxpool_k, dim3(256), dim3(256), 0, stream, x3, pooled);
    hipLaunchKernelGGL(fc_k, dim3(1), dim3(64), 0, stream, pooled, fcw, fcb, out);

    (void)in_sizes; (void)n_in; (void)out_size; (void)ws_size;
}

// Round 2
// 8559.712 us; speedup vs baseline: 1.2315x; 1.2315x over previous
//
#include <hip/hip_runtime.h>
#include <math.h>

// eval-mode BatchNorm3d scale: np.float32(1/sqrt(1+1e-5))
#define BN_S 0.9999950000374997f

__device__ __forceinline__ float silu_f(float x) {
    return __fdividef(x, 1.0f + __expf(-x));
}

// ---------------------------------------------------------------------------
// Prep: W_em = ew2 @ mw1[64:], W_mu = mw2 @ uw1, b_mu = mb2 @ uw1 + ub1
// ---------------------------------------------------------------------------
__global__ __launch_bounds__(64) void prep_w_k(
    const float* __restrict__ ew2, const float* __restrict__ mw1,
    const float* __restrict__ mw2, const float* __restrict__ uw1,
    const float* __restrict__ mb2, const float* __restrict__ ub1,
    float* __restrict__ W_em, float* __restrict__ W_mu, float* __restrict__ b_mu)
{
    const int k = blockIdx.x, c = threadIdx.x;
    float s = 0.f;
    for (int m = 0; m < 64; m++) s = fmaf(ew2[k*64 + m], mw1[(64 + m)*64 + c], s);
    W_em[k*64 + c] = s;
    float s2 = 0.f;
    for (int m = 0; m < 64; m++) s2 = fmaf(mw2[k*64 + m], uw1[m*64 + c], s2);
    W_mu[k*64 + c] = s2;
    if (k == 0) {
        float s3 = ub1[c];
        for (int m = 0; m < 64; m++) s3 = fmaf(mb2[m], uw1[m*64 + c], s3);
        b_mu[c] = s3;
    }
}

// ---------------------------------------------------------------------------
// Prep per-node / per-voxel tables.
// ---------------------------------------------------------------------------
__global__ __launch_bounds__(64) void prep_nodes_k(
    const float* __restrict__ node_embedding, const float* __restrict__ node_pos,
    const float* __restrict__ grid_pos, const float* __restrict__ ew1,
    const float* __restrict__ eb1, const float* __restrict__ mw1,
    const float* __restrict__ mb1, const float* __restrict__ eb2,
    float* __restrict__ a_node, float* __restrict__ g_vox, float* __restrict__ n_node)
{
    const int v = blockIdx.x, c = threadIdx.x;
    const float p0 = node_pos[v*3], p1 = node_pos[v*3 + 1], p2 = node_pos[v*3 + 2];
    a_node[v*64 + c] = fmaf(p0, ew1[c], fmaf(p1, ew1[64 + c], fmaf(p2, ew1[128 + c], eb1[c])));
    const float q0 = grid_pos[v*3], q1 = grid_pos[v*3 + 1], q2 = grid_pos[v*3 + 2];
    g_vox[v*64 + c] = fmaf(q0, ew1[192 + c], fmaf(q1, ew1[256 + c], q2 * ew1[320 + c]));
    float s = mb1[c];
    for (int k = 0; k < 64; k++) s = fmaf(node_embedding[v*64 + k], mw1[k*64 + c], s);
    for (int k = 0; k < 64; k++) s = fmaf(eb2[k], mw1[(64 + k)*64 + c], s);
    n_node[v*64 + c] = s;
}

// ---------------------------------------------------------------------------
// Edge kernel: one block per grid voxel j (edges contiguous per voxel).
// ---------------------------------------------------------------------------
__global__ __launch_bounds__(256) void edge_kernel(
    const int* __restrict__ edge_i,
    const float* __restrict__ a_node, const float* __restrict__ g_vox,
    const float* __restrict__ n_node, const float* __restrict__ W_em,
    const float* __restrict__ W_mu, const float* __restrict__ b_mu,
    const float* __restrict__ uw2, const float* __restrict__ ub2,
    float* __restrict__ x0)
{
    __shared__ float sW[64*64];
    __shared__ float sS1[64*68];
    __shared__ float sRed[16*64];
    __shared__ float sV1[64];
    __shared__ float sV2[64];

    const int j = blockIdx.x;
    const int t = threadIdx.x;

    {
        const float4* src = (const float4*)W_em;
        float4* dst = (float4*)sW;
        #pragma unroll
        for (int q = 0; q < 4; q++) dst[t + 256*q] = src[t + 256*q];
    }

    const int tr = t >> 4, tc = t & 15;
    const int ebase = j << 8;
    const float* gj = g_vox + j*64;
    float psum[4] = {0.f, 0.f, 0.f, 0.f};

    for (int T = 0; T < 4; T++) {
        __syncthreads();
        {
            const int r = t >> 2, sub = t & 3;
            const int i = edge_i[ebase + T*64 + r];
            const float4* ai = (const float4*)(a_node + i*64 + sub*16);
            const float4* gi = (const float4*)(gj + sub*16);
            float4* dst = (float4*)(sS1 + r*68 + sub*16);
            #pragma unroll
            for (int q = 0; q < 4; q++) {
                float4 a = ai[q], g = gi[q], o;
                o.x = silu_f(a.x + g.x); o.y = silu_f(a.y + g.y);
                o.z = silu_f(a.z + g.z); o.w = silu_f(a.w + g.w);
                dst[q] = o;
            }
        }
        __syncthreads();
        float acc[4][4];
        #pragma unroll
        for (int ri = 0; ri < 4; ri++) {
            const int i = edge_i[ebase + T*64 + tr*4 + ri];
            const float4 nv = *(const float4*)(n_node + i*64 + tc*4);
            acc[ri][0] = nv.x; acc[ri][1] = nv.y; acc[ri][2] = nv.z; acc[ri][3] = nv.w;
        }
        #pragma unroll
        for (int k = 0; k < 64; k += 4) {
            float sva[4][4], wva[4][4];
            #pragma unroll
            for (int ri = 0; ri < 4; ri++) {
                const float4 v = *(const float4*)(sS1 + (tr*4 + ri)*68 + k);
                sva[ri][0] = v.x; sva[ri][1] = v.y; sva[ri][2] = v.z; sva[ri][3] = v.w;
            }
            #pragma unroll
            for (int kk = 0; kk < 4; kk++) {
                const float4 v = *(const float4*)(sW + (k + kk)*64 + tc*4);
                wva[kk][0] = v.x; wva[kk][1] = v.y; wva[kk][2] = v.z; wva[kk][3] = v.w;
            }
            #pragma unroll
            for (int ri = 0; ri < 4; ri++)
                #pragma unroll
                for (int kk = 0; kk < 4; kk++)
                    #pragma unroll
                    for (int ci = 0; ci < 4; ci++)
                        acc[ri][ci] = fmaf(sva[ri][kk], wva[kk][ci], acc[ri][ci]);
        }
        #pragma unroll
        for (int ri = 0; ri < 4; ri++)
            #pragma unroll
            for (int ci = 0; ci < 4; ci++)
                psum[ci] += silu_f(acc[ri][ci]);
    }

    __syncthreads();
    *(float4*)(sRed + tr*64 + tc*4) = *(float4*)psum;
    __syncthreads();
    if (t < 64) {
        float s = 0.f;
        #pragma unroll
        for (int q = 0; q < 16; q++) s += sRed[q*64 + t];
        sV1[t] = s * (1.0f / 256.0f);
    }
    __syncthreads();
    if (t < 64) {
        float h = b_mu[t];
        for (int k = 0; k < 64; k++) h = fmaf(sV1[k], W_mu[k*64 + t], h);
        sV2[t] = silu_f(h);
    }
    __syncthreads();
    if (t < 64) {
        float g = ub2[t];
        for (int k = 0; k < 64; k++) g = fmaf(sV2[k], uw2[k*64 + t], g);
        x0[t*4096 + j] = g * BN_S;
    }
}

// ---------------------------------------------------------------------------
// Conv3D v2: NCDHW, 16^3, zero pad. Block = one d-plane (16x16 threads),
// COT output channels per thread, CI-split over grid.z (CIS channels each).
// Register-prefetch + double-buffered LDS: one __syncthreads per ci,
// global-load latency hidden under the FMA burst.
// MODE 0: write raw partial to pbuf[s][CO][4096]
// MODE 1: out = relu(conv*BN)      (final, S==1)
// MODE 2: out = conv*BN            (final, S==1)
// MODE 3: out = relu(conv*BN+add)  (final, S==1)
// ---------------------------------------------------------------------------
template<int K, int CITOT, int CIS, int COT, int MODE>
__global__ __launch_bounds__(256, 2) void conv3d_k(
    const float* __restrict__ in, const float* __restrict__ wt,
    const float* __restrict__ addsrc, float* __restrict__ out)
{
    constexpr int P = K / 2;
    constexpr int K2 = K * K;
    __shared__ float sl[2][K][256];
    const int d0 = blockIdx.x;
    const int cog = blockIdx.y;
    const int sidx = blockIdx.z;
    const int ci0 = sidx * CIS;
    const int t = threadIdx.x;
    const int h = t >> 4, w = t & 15;

    float acc[COT];
    #pragma unroll
    for (int c = 0; c < COT; c++) acc[c] = 0.f;

    // stage first input channel
    #pragma unroll
    for (int kd = 0; kd < K; kd++) {
        const int z = d0 + kd - P;
        sl[0][kd][t] = ((unsigned)z < 16u) ? in[(ci0*16 + z)*256 + t] : 0.f;
    }
    __syncthreads();

    int cur = 0;
    for (int cl = 0; cl < CIS; cl++) {
        const int ci = ci0 + cl;
        // prefetch next channel into registers (latency overlaps FMA burst)
        float pn[K];
        if (cl + 1 < CIS) {
            #pragma unroll
            for (int kd = 0; kd < K; kd++) {
                const int z = d0 + kd - P;
                pn[kd] = ((unsigned)z < 16u) ? in[((ci + 1)*16 + z)*256 + t] : 0.f;
            }
        }
        // FMA burst: COT independent accumulators, uniform (scalar) weights
        #pragma unroll
        for (int kd = 0; kd < K; kd++) {
            float vals[K2];
            #pragma unroll
            for (int kh = 0; kh < K; kh++)
                #pragma unroll
                for (int kw = 0; kw < K; kw++) {
                    const int hh = h + kh - P, ww = w + kw - P;
                    const bool ok = ((unsigned)hh < 16u) && ((unsigned)ww < 16u);
                    const int idx = ok ? (hh*16 + ww) : 0;
                    vals[kh*K + kw] = ok ? sl[cur][kd][idx] : 0.f;
                }
            #pragma unroll
            for (int c = 0; c < COT; c++) {
                const float* wp = wt + (((cog*COT + c)*CITOT + ci)*K + kd)*K2;
                #pragma unroll
                for (int q = 0; q < K2; q++) acc[c] = fmaf(vals[q], wp[q], acc[c]);
            }
        }
        if (cl + 1 < CIS) {
            #pragma unroll
            for (int kd = 0; kd < K; kd++) sl[cur ^ 1][kd][t] = pn[kd];
            __syncthreads();
            cur ^= 1;
        }
    }

    const int vox = d0*256 + t;
    #pragma unroll
    for (int c = 0; c < COT; c++) {
        const int co = cog*COT + c;
        if (MODE == 0) {
            out[(sidx*(gridDim.y*COT) + co)*4096 + vox] = acc[c];
        } else {
            float v = acc[c] * BN_S;
            const int o = co*4096 + vox;
            if (MODE == 1) v = fmaxf(v, 0.f);
            if (MODE == 3) v = fmaxf(v + addsrc[o], 0.f);
            out[o] = v;
        }
    }
}

// ---------------------------------------------------------------------------
// Reduce S partial slabs + BN + activation/residual. float4 per thread.
// RMODE 1: relu(BN*sum); RMODE 2: BN*sum; RMODE 3: relu(BN*sum + add)
// grid = CO*4096/1024, block 256
// ---------------------------------------------------------------------------
template<int RMODE>
__global__ __launch_bounds__(256) void reduce_k(
    const float* __restrict__ pbuf, const float* __restrict__ addsrc,
    float* __restrict__ out, int S, int total)
{
    const int idx4 = blockIdx.x*256 + threadIdx.x;
    float4 a = ((const float4*)pbuf)[idx4];
    const int stride4 = total >> 2;
    for (int s = 1; s < S; s++) {
        float4 b = ((const float4*)pbuf)[s*stride4 + idx4];
        a.x += b.x; a.y += b.y; a.z += b.z; a.w += b.w;
    }
    a.x *= BN_S; a.y *= BN_S; a.z *= BN_S; a.w *= BN_S;
    if (RMODE == 3) {
        float4 ad = ((const float4*)addsrc)[idx4];
        a.x += ad.x; a.y += ad.y; a.z += ad.z; a.w += ad.w;
    }
    if (RMODE == 1 || RMODE == 3) {
        a.x = fmaxf(a.x, 0.f); a.y = fmaxf(a.y, 0.f);
        a.z = fmaxf(a.z, 0.f); a.w = fmaxf(a.w, 0.f);
    }
    ((float4*)out)[idx4] = a;
}

// ---------------------------------------------------------------------------
__global__ __launch_bounds__(256) void maxpool_k(
    const float* __restrict__ x, float* __restrict__ pooled)
{
    const int c = blockIdx.x;
    float m = -3.4e38f;
    for (int v = threadIdx.x; v < 4096; v += 256) m = fmaxf(m, x[c*4096 + v]);
    #pragma unroll
    for (int off = 32; off > 0; off >>= 1) m = fmaxf(m, __shfl_down(m, off, 64));
    __shared__ float sm[4];
    if ((threadIdx.x & 63) == 0) sm[threadIdx.x >> 6] = m;
    __syncthreads();
    if (threadIdx.x == 0)
        pooled[c] = fmaxf(fmaxf(sm[0], sm[1]), fmaxf(sm[2], sm[3]));
}

__global__ __launch_bounds__(64) void fc_k(
    const float* __restrict__ pooled, const float* __restrict__ fcw,
    const float* __restrict__ fcb, float* __restrict__ out)
{
    __shared__ float sp[256];
    const int t = threadIdx.x;
    for (int q = t; q < 256; q += 64) sp[q] = pooled[q];
    __syncthreads();
    if (t < 20) {
        float s = fcb[t];
        for (int c = 0; c < 256; c++) s = fmaf(sp[c], fcw[c*20 + t], s);
        out[t] = s;
    }
}

// ---------------------------------------------------------------------------
extern "C" void kernel_launch(void* const* d_in, const int* in_sizes, int n_in,
                              void* d_out, int out_size, void* d_ws, size_t ws_size,
                              hipStream_t stream)
{
    const float* node_embedding = (const float*)d_in[0];
    const float* node_pos       = (const float*)d_in[1];
    const float* grid_pos       = (const float*)d_in[2];
    const int*   edge_index     = (const int*)d_in[3];
    const float* ew1 = (const float*)d_in[4];
    const float* eb1 = (const float*)d_in[5];
    const float* ew2 = (const float*)d_in[6];
    const float* eb2 = (const float*)d_in[7];
    const float* mw1 = (const float*)d_in[8];
    const float* mb1 = (const float*)d_in[9];
    const float* mw2 = (const float*)d_in[10];
    const float* mb2 = (const float*)d_in[11];
    const float* uw1 = (const float*)d_in[12];
    const float* ub1 = (const float*)d_in[13];
    const float* uw2 = (const float*)d_in[14];
    const float* ub2 = (const float*)d_in[15];
    const float* c1a = (const float*)d_in[16];
    const float* c1b = (const float*)d_in[17];
    const float* c1s = (const float*)d_in[18];
    const float* c2a = (const float*)d_in[19];
    const float* c2b = (const float*)d_in[20];
    const float* c2s = (const float*)d_in[21];
    const float* c3a = (const float*)d_in[22];
    const float* c3b = (const float*)d_in[23];
    const float* c3s = (const float*)d_in[24];
    const float* fcw = (const float*)d_in[25];
    const float* fcb = (const float*)d_in[26];
    float* out = (float*)d_out;
    const int* edge_i = edge_index;

    float* ws = (float*)d_ws;
    float* a_node = ws; ws += 4096*64;
    float* g_vox  = ws; ws += 4096*64;
    float* n_node = ws; ws += 4096*64;
    float* W_em   = ws; ws += 64*64;
    float* W_mu   = ws; ws += 64*64;
    float* b_mu   = ws; ws += 64;
    float* x0 = ws; ws += 64*4096;
    float* t1 = ws; ws += 64*4096;
    float* u1 = ws; ws += 64*4096;
    float* x1 = ws; ws += 64*4096;
    float* t2 = ws; ws += 128*4096;
    float* u2 = ws; ws += 128*4096;
    float* x2 = ws; ws += 128*4096;
    float* t3 = ws; ws += 256*4096;
    float* u3 = ws; ws += 256*4096;
    float* x3 = ws; ws += 256*4096;
    float* pooled = ws; ws += 256;
    float* pbuf = t3;   // partial slabs; t3 is dead until c3a (max need 1M floats)

    hipLaunchKernelGGL(prep_w_k, dim3(64), dim3(64), 0, stream,
                       ew2, mw1, mw2, uw1, mb2, ub1, W_em, W_mu, b_mu);
    hipLaunchKernelGGL(prep_nodes_k, dim3(4096), dim3(64), 0, stream,
                       node_embedding, node_pos, grid_pos, ew1, eb1, mw1, mb1, eb2,
                       a_node, g_vox, n_node);
    hipLaunchKernelGGL(edge_kernel, dim3(4096), dim3(256), 0, stream,
                       edge_i, a_node, g_vox, n_node, W_em, W_mu, b_mu, uw2, ub2, x0);

    // Block 1: 64 -> 64  (CI split 4 -> 512 blocks each)
    hipLaunchKernelGGL((conv3d_k<3,64,16,8,0>), dim3(16,8,4), dim3(256), 0, stream, x0, c1a, nullptr, pbuf);
    hipLaunchKernelGGL((reduce_k<1>), dim3(256), dim3(256), 0, stream, pbuf, nullptr, t1, 4, 64*4096);
    hipLaunchKernelGGL((conv3d_k<3,64,16,8,0>), dim3(16,8,4), dim3(256), 0, stream, t1, c1b, nullptr, pbuf);
    hipLaunchKernelGGL((reduce_k<2>), dim3(256), dim3(256), 0, stream, pbuf, nullptr, u1, 4, 64*4096);
    hipLaunchKernelGGL((conv3d_k<5,64,16,8,0>), dim3(16,8,4), dim3(256), 0, stream, x0, c1s, nullptr, pbuf);
    hipLaunchKernelGGL((reduce_k<3>), dim3(256), dim3(256), 0, stream, pbuf, u1, x1, 4, 64*4096);

    // Block 2: 64 -> 128  (CI split 2 -> 512 blocks each)
    hipLaunchKernelGGL((conv3d_k<3,64,32,8,0>),  dim3(16,16,2), dim3(256), 0, stream, x1, c2a, nullptr, pbuf);
    hipLaunchKernelGGL((reduce_k<1>), dim3(512), dim3(256), 0, stream, pbuf, nullptr, t2, 2, 128*4096);
    hipLaunchKernelGGL((conv3d_k<3,128,64,8,0>), dim3(16,16,2), dim3(256), 0, stream, t2, c2b, nullptr, pbuf);
    hipLaunchKernelGGL((reduce_k<2>), dim3(512), dim3(256), 0, stream, pbuf, nullptr, u2, 2, 128*4096);
    hipLaunchKernelGGL((conv3d_k<5,64,32,8,0>),  dim3(16,16,2), dim3(256), 0, stream, x1, c2s, nullptr, pbuf);
    hipLaunchKernelGGL((reduce_k<3>), dim3(512), dim3(256), 0, stream, pbuf, u2, x2, 2, 128*4096);

    // Block 3: 128 -> 256  (no split; 512 blocks)
    hipLaunchKernelGGL((conv3d_k<3,128,128,8,1>), dim3(16,32,1), dim3(256), 0, stream, x2, c3a, nullptr, t3);
    hipLaunchKernelGGL((conv3d_k<3,256,256,8,2>), dim3(16,32,1), dim3(256), 0, stream, t3, c3b, nullptr, u3);
    hipLaunchKernelGGL((conv3d_k<5,128,128,8,3>), dim3(16,32,1), dim3(256), 0, stream, x2, c3s, u3, x3);

    hipLaunchKernelGGL(maxpool_k, dim3(256), dim3(256), 0, stream, x3, pooled);
    hipLaunchKernelGGL(fc_k, dim3(1), dim3(64), 0, stream, pooled, fcw, fcb, out);

    (void)in_sizes; (void)n_in; (void)out_size; (void)ws_size;
}

// Round 3
// 756.833 us; speedup vs baseline: 13.9287x; 11.3099x over previous
//
#include <hip/hip_runtime.h>
#include <math.h>

// eval-mode BatchNorm3d scale: np.float32(1/sqrt(1+1e-5))
#define BN_S 0.9999950000374997f

typedef _Float16 half8 __attribute__((ext_vector_type(8)));
typedef float f32x4 __attribute__((ext_vector_type(4)));

__device__ __forceinline__ float silu_f(float x) {
    return __fdividef(x, 1.0f + __expf(-x));
}

// ---------------------------------------------------------------------------
// Prep: W_em = ew2 @ mw1[64:], W_mu = mw2 @ uw1, b_mu = mb2 @ uw1 + ub1
// ---------------------------------------------------------------------------
__global__ __launch_bounds__(64) void prep_w_k(
    const float* __restrict__ ew2, const float* __restrict__ mw1,
    const float* __restrict__ mw2, const float* __restrict__ uw1,
    const float* __restrict__ mb2, const float* __restrict__ ub1,
    float* __restrict__ W_em, float* __restrict__ W_mu, float* __restrict__ b_mu)
{
    const int k = blockIdx.x, c = threadIdx.x;
    float s = 0.f;
    for (int m = 0; m < 64; m++) s = fmaf(ew2[k*64 + m], mw1[(64 + m)*64 + c], s);
    W_em[k*64 + c] = s;
    float s2 = 0.f;
    for (int m = 0; m < 64; m++) s2 = fmaf(mw2[k*64 + m], uw1[m*64 + c], s2);
    W_mu[k*64 + c] = s2;
    if (k == 0) {
        float s3 = ub1[c];
        for (int m = 0; m < 64; m++) s3 = fmaf(mb2[m], uw1[m*64 + c], s3);
        b_mu[c] = s3;
    }
}

// ---------------------------------------------------------------------------
// Prep per-node / per-voxel tables.
// ---------------------------------------------------------------------------
__global__ __launch_bounds__(64) void prep_nodes_k(
    const float* __restrict__ node_embedding, const float* __restrict__ node_pos,
    const float* __restrict__ grid_pos, const float* __restrict__ ew1,
    const float* __restrict__ eb1, const float* __restrict__ mw1,
    const float* __restrict__ mb1, const float* __restrict__ eb2,
    float* __restrict__ a_node, float* __restrict__ g_vox, float* __restrict__ n_node)
{
    const int v = blockIdx.x, c = threadIdx.x;
    const float p0 = node_pos[v*3], p1 = node_pos[v*3 + 1], p2 = node_pos[v*3 + 2];
    a_node[v*64 + c] = fmaf(p0, ew1[c], fmaf(p1, ew1[64 + c], fmaf(p2, ew1[128 + c], eb1[c])));
    const float q0 = grid_pos[v*3], q1 = grid_pos[v*3 + 1], q2 = grid_pos[v*3 + 2];
    g_vox[v*64 + c] = fmaf(q0, ew1[192 + c], fmaf(q1, ew1[256 + c], q2 * ew1[320 + c]));
    float s = mb1[c];
    for (int k = 0; k < 64; k++) s = fmaf(node_embedding[v*64 + k], mw1[k*64 + c], s);
    for (int k = 0; k < 64; k++) s = fmaf(eb2[k], mw1[(64 + k)*64 + c], s);
    n_node[v*64 + c] = s;
}

// ---------------------------------------------------------------------------
// Edge kernel: one block per grid voxel j (edges contiguous per voxel).
// ---------------------------------------------------------------------------
__global__ __launch_bounds__(256) void edge_kernel(
    const int* __restrict__ edge_i,
    const float* __restrict__ a_node, const float* __restrict__ g_vox,
    const float* __restrict__ n_node, const float* __restrict__ W_em,
    const float* __restrict__ W_mu, const float* __restrict__ b_mu,
    const float* __restrict__ uw2, const float* __restrict__ ub2,
    float* __restrict__ x0)
{
    __shared__ float sW[64*64];
    __shared__ float sS1[64*68];
    __shared__ float sRed[16*64];
    __shared__ float sV1[64];
    __shared__ float sV2[64];

    const int j = blockIdx.x;
    const int t = threadIdx.x;

    {
        const float4* src = (const float4*)W_em;
        float4* dst = (float4*)sW;
        #pragma unroll
        for (int q = 0; q < 4; q++) dst[t + 256*q] = src[t + 256*q];
    }

    const int tr = t >> 4, tc = t & 15;
    const int ebase = j << 8;
    const float* gj = g_vox + j*64;
    float psum[4] = {0.f, 0.f, 0.f, 0.f};

    for (int T = 0; T < 4; T++) {
        __syncthreads();
        {
            const int r = t >> 2, sub = t & 3;
            const int i = edge_i[ebase + T*64 + r];
            const float4* ai = (const float4*)(a_node + i*64 + sub*16);
            const float4* gi = (const float4*)(gj + sub*16);
            float4* dst = (float4*)(sS1 + r*68 + sub*16);
            #pragma unroll
            for (int q = 0; q < 4; q++) {
                float4 a = ai[q], g = gi[q], o;
                o.x = silu_f(a.x + g.x); o.y = silu_f(a.y + g.y);
                o.z = silu_f(a.z + g.z); o.w = silu_f(a.w + g.w);
                dst[q] = o;
            }
        }
        __syncthreads();
        float acc[4][4];
        #pragma unroll
        for (int ri = 0; ri < 4; ri++) {
            const int i = edge_i[ebase + T*64 + tr*4 + ri];
            const float4 nv = *(const float4*)(n_node + i*64 + tc*4);
            acc[ri][0] = nv.x; acc[ri][1] = nv.y; acc[ri][2] = nv.z; acc[ri][3] = nv.w;
        }
        #pragma unroll
        for (int k = 0; k < 64; k += 4) {
            float sva[4][4], wva[4][4];
            #pragma unroll
            for (int ri = 0; ri < 4; ri++) {
                const float4 v = *(const float4*)(sS1 + (tr*4 + ri)*68 + k);
                sva[ri][0] = v.x; sva[ri][1] = v.y; sva[ri][2] = v.z; sva[ri][3] = v.w;
            }
            #pragma unroll
            for (int kk = 0; kk < 4; kk++) {
                const float4 v = *(const float4*)(sW + (k + kk)*64 + tc*4);
                wva[kk][0] = v.x; wva[kk][1] = v.y; wva[kk][2] = v.z; wva[kk][3] = v.w;
            }
            #pragma unroll
            for (int ri = 0; ri < 4; ri++)
                #pragma unroll
                for (int kk = 0; kk < 4; kk++)
                    #pragma unroll
                    for (int ci = 0; ci < 4; ci++)
                        acc[ri][ci] = fmaf(sva[ri][kk], wva[kk][ci], acc[ri][ci]);
        }
        #pragma unroll
        for (int ri = 0; ri < 4; ri++)
            #pragma unroll
            for (int ci = 0; ci < 4; ci++)
                psum[ci] += silu_f(acc[ri][ci]);
    }

    __syncthreads();
    *(float4*)(sRed + tr*64 + tc*4) = *(float4*)psum;
    __syncthreads();
    if (t < 64) {
        float s = 0.f;
        #pragma unroll
        for (int q = 0; q < 16; q++) s += sRed[q*64 + t];
        sV1[t] = s * (1.0f / 256.0f);
    }
    __syncthreads();
    if (t < 64) {
        float h = b_mu[t];
        for (int k = 0; k < 64; k++) h = fmaf(sV1[k], W_mu[k*64 + t], h);
        sV2[t] = silu_f(h);
    }
    __syncthreads();
    if (t < 64) {
        float g = ub2[t];
        for (int k = 0; k < 64; k++) g = fmaf(sV2[k], uw2[k*64 + t], g);
        x0[t*4096 + j] = g * BN_S;
    }
}

// ---------------------------------------------------------------------------
// Weight transpose + fp16 hi/lo split.
// src: [CO][CI][K^3] fp32  ->  dst: [K^3][CO][CI] u32 = hi | (lo<<16)
// grid(CO, CI/32), block 256
// ---------------------------------------------------------------------------
template<int TAPS>
__global__ __launch_bounds__(256) void wsplit_k(
    const float* __restrict__ w, uint32_t* __restrict__ dst, int CO, int CI)
{
    __shared__ float s[32*TAPS];
    const int co = blockIdx.x, cig = blockIdx.y, t = threadIdx.x;
    const float* src = w + ((size_t)co*CI + cig*32)*TAPS;
    for (int m = t; m < 32*TAPS; m += 256) s[m] = src[m];
    __syncthreads();
    for (int m = t; m < 32*TAPS; m += 256) {
        const int tap = m >> 5, ciL = m & 31;
        const float x = s[ciL*TAPS + tap];
        const _Float16 h = (_Float16)x;
        const _Float16 l = (_Float16)(x - (float)h);
        const uint32_t u = (uint32_t)__builtin_bit_cast(unsigned short, h)
                         | ((uint32_t)__builtin_bit_cast(unsigned short, l) << 16);
        dst[((size_t)tap*CO + co)*CI + cig*32 + ciL] = u;
    }
}

// ---------------------------------------------------------------------------
// Conv3D via MFMA shift-GEMM, fp16 hi/lo split (3-term), kd-split partials.
// Block: (d-plane d0, 64-co group, kd). 256 threads = 4 waves; wave owns
// 64 co x 64 vox (4x4 frags of 16x16), K(ci) chunked by 32.
// Writes raw fp32 partial to slab[kd][CO][4096].
// ---------------------------------------------------------------------------
template<int KK, int CI>
__global__ __launch_bounds__(256) void conv_mfma_k(
    const float* __restrict__ in,       // [CI][4096]
    const uint32_t* __restrict__ wsp,   // [KK^3][CO][CI] hi|lo u32
    float* __restrict__ slab)           // [KK][CO][4096]
{
    constexpr int P = KK/2, K2 = KK*KK;
    const int d0 = blockIdx.x, coG = blockIdx.y, kd = blockIdx.z;
    const int CO = gridDim.y * 64;
    const int t = threadIdx.x;
    const int lane = t & 63, wv = t >> 6;
    const int ln15 = lane & 15, kg = lane >> 4;

    float* sout = slab + ((size_t)kd*CO + coG*64)*4096 + d0*256;
    const int z = d0 + kd - P;
    if ((unsigned)z >= 16u) {   // OOB depth plane -> zero partial
        for (int m = t; m < 64*256; m += 256) sout[(m>>8)*4096 + (m & 255)] = 0.f;
        return;
    }

    __shared__ __align__(16) _Float16 Xh[4*256*8];   // [ci_oct][vox][8]
    __shared__ __align__(16) _Float16 Xl[4*256*8];
    __shared__ __align__(16) _Float16 Ah[2][64*40];  // [buf][co*40 + ci] (pad 40)
    __shared__ __align__(16) _Float16 Al[2][64*40];
    __shared__ __align__(16) _Float16 zbuf[8];
    if (t < 8) zbuf[t] = (_Float16)0.f;

    f32x4 acc[4][4] = {{0}};   // [coF][voxF]

    auto stageA = [&](int t2, int b) {
        const uint32_t* wt = wsp + ((size_t)(kd*K2 + t2)*CO + coG*64)*CI;
        #pragma unroll
        for (int q = 0; q < 4; q++) {
            const int p = q*256 + t;          // pair index 0..1023
            const int co = p >> 4;
            const int ci2 = (p & 15)*2;
            const uint2 uu = *(const uint2*)&wt[(size_t)co*CI + ci2];  // ci offset added by caller via wt+c0
            const uint32_t hh = (uu.x & 0xffffu) | (uu.y << 16);
            const uint32_t ll = (uu.x >> 16) | (uu.y & 0xffff0000u);
            *(uint32_t*)&Ah[b][co*40 + ci2] = hh;
            *(uint32_t*)&Al[b][co*40 + ci2] = ll;
        }
    };

    int gpar = 0;   // running A-buffer parity
    for (int c0 = 0; c0 < CI; c0 += 32) {
        // ---- stage X chunk (32 ci of plane z), fp32 -> hi/lo f16 ----
        {
            const float* src = in + (size_t)c0*4096 + z*256 + t;
            #pragma unroll
            for (int oct = 0; oct < 4; oct++) {
                half8 hv, lv;
                #pragma unroll
                for (int j = 0; j < 8; j++) {
                    const float x = src[(size_t)(oct*8 + j)*4096];
                    const _Float16 h = (_Float16)x;
                    hv[j] = h;
                    lv[j] = (_Float16)(x - (float)h);
                }
                *(half8*)&Xh[(oct*256 + t)*8] = hv;
                *(half8*)&Xl[(oct*256 + t)*8] = lv;
            }
        }
        // stage A for first tap of this chunk into current parity buffer
        {
            const uint32_t* wt0 = wsp + ((size_t)(kd*K2 + 0)*CO + coG*64)*CI + c0;
            // inline stageA with explicit base (c0 folded)
            #pragma unroll
            for (int q = 0; q < 4; q++) {
                const int p = q*256 + t;
                const int co = p >> 4;
                const int ci2 = (p & 15)*2;
                const uint2 uu = *(const uint2*)&wt0[(size_t)co*CI + ci2];
                const uint32_t hh = (uu.x & 0xffffu) | (uu.y << 16);
                const uint32_t ll = (uu.x >> 16) | (uu.y & 0xffff0000u);
                *(uint32_t*)&Ah[gpar][co*40 + ci2] = hh;
                *(uint32_t*)&Al[gpar][co*40 + ci2] = ll;
            }
        }
        __syncthreads();

        for (int t2 = 0; t2 < K2; t2++) {
            const int b = gpar;
            // prefetch-stage next tap's A into the other buffer
            if (t2 + 1 < K2) {
                const uint32_t* wt1 = wsp + ((size_t)(kd*K2 + t2 + 1)*CO + coG*64)*CI + c0;
                #pragma unroll
                for (int q = 0; q < 4; q++) {
                    const int p = q*256 + t;
                    const int co = p >> 4;
                    const int ci2 = (p & 15)*2;
                    const uint2 uu = *(const uint2*)&wt1[(size_t)co*CI + ci2];
                    const uint32_t hh = (uu.x & 0xffffu) | (uu.y << 16);
                    const uint32_t ll = (uu.x >> 16) | (uu.y & 0xffff0000u);
                    *(uint32_t*)&Ah[b^1][co*40 + ci2] = hh;
                    *(uint32_t*)&Al[b^1][co*40 + ci2] = ll;
                }
            }
            // ---- compute tap t2 from buffer b ----
            const int kh = t2 / KK, kw = t2 % KK;
            half8 Afh[4], Afl[4];
            #pragma unroll
            for (int cf = 0; cf < 4; cf++) {
                const int off = (cf*16 + ln15)*40 + kg*8;
                Afh[cf] = *(const half8*)&Ah[b][off];
                Afl[cf] = *(const half8*)&Al[b][off];
            }
            #pragma unroll
            for (int f = 0; f < 4; f++) {
                const int h_in = wv*4 + f + kh - P;
                if ((unsigned)h_in < 16u) {
                    const int w_in = ln15 + kw - P;
                    const bool ok = (unsigned)w_in < 16u;
                    const int v_in = h_in*16 + w_in;
                    const half8* ph = ok ? (const half8*)&Xh[(kg*256 + v_in)*8]
                                         : (const half8*)zbuf;
                    const half8* pl = ok ? (const half8*)&Xl[(kg*256 + v_in)*8]
                                         : (const half8*)zbuf;
                    const half8 Bh = *ph;
                    const half8 Bl = *pl;
                    #pragma unroll
                    for (int cf = 0; cf < 4; cf++) {
                        acc[cf][f] = __builtin_amdgcn_mfma_f32_16x16x32_f16(Afh[cf], Bh, acc[cf][f], 0, 0, 0);
                        acc[cf][f] = __builtin_amdgcn_mfma_f32_16x16x32_f16(Afh[cf], Bl, acc[cf][f], 0, 0, 0);
                        acc[cf][f] = __builtin_amdgcn_mfma_f32_16x16x32_f16(Afl[cf], Bh, acc[cf][f], 0, 0, 0);
                    }
                }
            }
            gpar ^= 1;
            __syncthreads();
        }
    }

    // ---- epilogue: C frag layout col=lane&15, row=(lane>>4)*4+reg ----
    #pragma unroll
    for (int cf = 0; cf < 4; cf++)
        #pragma unroll
        for (int f = 0; f < 4; f++)
            #pragma unroll
            for (int r = 0; r < 4; r++) {
                const int co = cf*16 + kg*4 + r;
                const int vox = wv*64 + f*16 + ln15;
                sout[(size_t)co*4096 + vox] = acc[cf][f][r];
            }
}

// ---------------------------------------------------------------------------
// Reduce S partial slabs + BN + activation/residual. float4 per thread.
// RMODE 1: relu(BN*sum); RMODE 2: BN*sum; RMODE 3: relu(BN*sum + add)
// ---------------------------------------------------------------------------
template<int RMODE>
__global__ __launch_bounds__(256) void reduce_k(
    const float* __restrict__ pbuf, const float* __restrict__ addsrc,
    float* __restrict__ out, int S, int total)
{
    const int idx4 = blockIdx.x*256 + threadIdx.x;
    float4 a = ((const float4*)pbuf)[idx4];
    const int stride4 = total >> 2;
    for (int s = 1; s < S; s++) {
        float4 b = ((const float4*)pbuf)[s*stride4 + idx4];
        a.x += b.x; a.y += b.y; a.z += b.z; a.w += b.w;
    }
    a.x *= BN_S; a.y *= BN_S; a.z *= BN_S; a.w *= BN_S;
    if (RMODE == 3) {
        float4 ad = ((const float4*)addsrc)[idx4];
        a.x += ad.x; a.y += ad.y; a.z += ad.z; a.w += ad.w;
    }
    if (RMODE == 1 || RMODE == 3) {
        a.x = fmaxf(a.x, 0.f); a.y = fmaxf(a.y, 0.f);
        a.z = fmaxf(a.z, 0.f); a.w = fmaxf(a.w, 0.f);
    }
    ((float4*)out)[idx4] = a;
}

// ---------------------------------------------------------------------------
__global__ __launch_bounds__(256) void maxpool_k(
    const float* __restrict__ x, float* __restrict__ pooled)
{
    const int c = blockIdx.x;
    float m = -3.4e38f;
    for (int v = threadIdx.x; v < 4096; v += 256) m = fmaxf(m, x[c*4096 + v]);
    #pragma unroll
    for (int off = 32; off > 0; off >>= 1) m = fmaxf(m, __shfl_down(m, off, 64));
    __shared__ float sm[4];
    if ((threadIdx.x & 63) == 0) sm[threadIdx.x >> 6] = m;
    __syncthreads();
    if (threadIdx.x == 0)
        pooled[c] = fmaxf(fmaxf(sm[0], sm[1]), fmaxf(sm[2], sm[3]));
}

__global__ __launch_bounds__(64) void fc_k(
    const float* __restrict__ pooled, const float* __restrict__ fcw,
    const float* __restrict__ fcb, float* __restrict__ out)
{
    __shared__ float sp[256];
    const int t = threadIdx.x;
    for (int q = t; q < 256; q += 64) sp[q] = pooled[q];
    __syncthreads();
    if (t < 20) {
        float s = fcb[t];
        for (int c = 0; c < 256; c++) s = fmaf(sp[c], fcw[c*20 + t], s);
        out[t] = s;
    }
}

// ---------------------------------------------------------------------------
extern "C" void kernel_launch(void* const* d_in, const int* in_sizes, int n_in,
                              void* d_out, int out_size, void* d_ws, size_t ws_size,
                              hipStream_t stream)
{
    const float* node_embedding = (const float*)d_in[0];
    const float* node_pos       = (const float*)d_in[1];
    const float* grid_pos       = (const float*)d_in[2];
    const int*   edge_index     = (const int*)d_in[3];
    const float* ew1 = (const float*)d_in[4];
    const float* eb1 = (const float*)d_in[5];
    const float* ew2 = (const float*)d_in[6];
    const float* eb2 = (const float*)d_in[7];
    const float* mw1 = (const float*)d_in[8];
    const float* mb1 = (const float*)d_in[9];
    const float* mw2 = (const float*)d_in[10];
    const float* mb2 = (const float*)d_in[11];
    const float* uw1 = (const float*)d_in[12];
    const float* ub1 = (const float*)d_in[13];
    const float* uw2 = (const float*)d_in[14];
    const float* ub2 = (const float*)d_in[15];
    const float* c1a = (const float*)d_in[16];
    const float* c1b = (const float*)d_in[17];
    const float* c1s = (const float*)d_in[18];
    const float* c2a = (const float*)d_in[19];
    const float* c2b = (const float*)d_in[20];
    const float* c2s = (const float*)d_in[21];
    const float* c3a = (const float*)d_in[22];
    const float* c3b = (const float*)d_in[23];
    const float* c3s = (const float*)d_in[24];
    const float* fcw = (const float*)d_in[25];
    const float* fcb = (const float*)d_in[26];
    float* out = (float*)d_out;
    const int* edge_i = edge_index;

    float* ws = (float*)d_ws;
    float* a_node = ws; ws += 4096*64;
    float* g_vox  = ws; ws += 4096*64;
    float* n_node = ws; ws += 4096*64;
    float* W_em   = ws; ws += 64*64;
    float* W_mu   = ws; ws += 64*64;
    float* b_mu   = ws; ws += 64;
    float* x0 = ws; ws += 64*4096;
    float* x1 = ws; ws += 64*4096;
    float* x2 = ws; ws += 128*4096;
    float* x3 = ws; ws += 256*4096;
    float* tbuf = ws; ws += 256*4096;   // shared temp for t1/t2/t3
    float* ubuf = ws; ws += 256*4096;   // shared temp for u1/u2/u3
    float* slab = ws; ws += 5*256*4096; // kd-split partials (max c3s: 5*1M)
    float* pooled = ws; ws += 256;
    uint32_t* wsp = (uint32_t*)ws;      // split weights, 9.17M u32
    uint32_t* w1a = wsp;                uint32_t* w1b = w1a + 27*64*64;
    uint32_t* w1s = w1b + 27*64*64;     uint32_t* w2a = w1s + 125*64*64;
    uint32_t* w2b = w2a + 27*128*64;    uint32_t* w2s = w2b + 27*128*128;
    uint32_t* w3a = w2s + 125*128*64;   uint32_t* w3b = w3a + 27*256*128;
    uint32_t* w3s = w3b + 27*256*256;

    // ---- weight transpose + split (independent of activations) ----
    hipLaunchKernelGGL((wsplit_k<27>),  dim3(64,2),  dim3(256), 0, stream, c1a, w1a, 64, 64);
    hipLaunchKernelGGL((wsplit_k<27>),  dim3(64,2),  dim3(256), 0, stream, c1b, w1b, 64, 64);
    hipLaunchKernelGGL((wsplit_k<125>), dim3(64,2),  dim3(256), 0, stream, c1s, w1s, 64, 64);
    hipLaunchKernelGGL((wsplit_k<27>),  dim3(128,2), dim3(256), 0, stream, c2a, w2a, 128, 64);
    hipLaunchKernelGGL((wsplit_k<27>),  dim3(128,4), dim3(256), 0, stream, c2b, w2b, 128, 128);
    hipLaunchKernelGGL((wsplit_k<125>), dim3(128,2), dim3(256), 0, stream, c2s, w2s, 128, 64);
    hipLaunchKernelGGL((wsplit_k<27>),  dim3(256,4), dim3(256), 0, stream, c3a, w3a, 256, 128);
    hipLaunchKernelGGL((wsplit_k<27>),  dim3(256,8), dim3(256), 0, stream, c3b, w3b, 256, 256);
    hipLaunchKernelGGL((wsplit_k<125>), dim3(256,4), dim3(256), 0, stream, c3s, w3s, 256, 128);

    // ---- MPNN ----
    hipLaunchKernelGGL(prep_w_k, dim3(64), dim3(64), 0, stream,
                       ew2, mw1, mw2, uw1, mb2, ub1, W_em, W_mu, b_mu);
    hipLaunchKernelGGL(prep_nodes_k, dim3(4096), dim3(64), 0, stream,
                       node_embedding, node_pos, grid_pos, ew1, eb1, mw1, mb1, eb2,
                       a_node, g_vox, n_node);
    hipLaunchKernelGGL(edge_kernel, dim3(4096), dim3(256), 0, stream,
                       edge_i, a_node, g_vox, n_node, W_em, W_mu, b_mu, uw2, ub2, x0);

    // ---- ResNet3D: conv_mfma(kd-split) + reduce ----
    // Block 1: 64 -> 64
    hipLaunchKernelGGL((conv_mfma_k<3,64>), dim3(16,1,3), dim3(256), 0, stream, x0, w1a, slab);
    hipLaunchKernelGGL((reduce_k<1>), dim3(256), dim3(256), 0, stream, slab, nullptr, tbuf, 3, 64*4096);
    hipLaunchKernelGGL((conv_mfma_k<3,64>), dim3(16,1,3), dim3(256), 0, stream, tbuf, w1b, slab);
    hipLaunchKernelGGL((reduce_k<2>), dim3(256), dim3(256), 0, stream, slab, nullptr, ubuf, 3, 64*4096);
    hipLaunchKernelGGL((conv_mfma_k<5,64>), dim3(16,1,5), dim3(256), 0, stream, x0, w1s, slab);
    hipLaunchKernelGGL((reduce_k<3>), dim3(256), dim3(256), 0, stream, slab, ubuf, x1, 5, 64*4096);
    // Block 2: 64 -> 128
    hipLaunchKernelGGL((conv_mfma_k<3,64>),  dim3(16,2,3), dim3(256), 0, stream, x1, w2a, slab);
    hipLaunchKernelGGL((reduce_k<1>), dim3(512), dim3(256), 0, stream, slab, nullptr, tbuf, 3, 128*4096);
    hipLaunchKernelGGL((conv_mfma_k<3,128>), dim3(16,2,3), dim3(256), 0, stream, tbuf, w2b, slab);
    hipLaunchKernelGGL((reduce_k<2>), dim3(512), dim3(256), 0, stream, slab, nullptr, ubuf, 3, 128*4096);
    hipLaunchKernelGGL((conv_mfma_k<5,64>),  dim3(16,2,5), dim3(256), 0, stream, x1, w2s, slab);
    hipLaunchKernelGGL((reduce_k<3>), dim3(512), dim3(256), 0, stream, slab, ubuf, x2, 5, 128*4096);
    // Block 3: 128 -> 256
    hipLaunchKernelGGL((conv_mfma_k<3,128>), dim3(16,4,3), dim3(256), 0, stream, x2, w3a, slab);
    hipLaunchKernelGGL((reduce_k<1>), dim3(1024), dim3(256), 0, stream, slab, nullptr, tbuf, 3, 256*4096);
    hipLaunchKernelGGL((conv_mfma_k<3,256>), dim3(16,4,3), dim3(256), 0, stream, tbuf, w3b, slab);
    hipLaunchKernelGGL((reduce_k<2>), dim3(1024), dim3(256), 0, stream, slab, nullptr, ubuf, 3, 256*4096);
    hipLaunchKernelGGL((conv_mfma_k<5,128>), dim3(16,4,5), dim3(256), 0, stream, x2, w3s, slab);
    hipLaunchKernelGGL((reduce_k<3>), dim3(1024), dim3(256), 0, stream, slab, ubuf, x3, 5, 256*4096);

    hipLaunchKernelGGL(maxpool_k, dim3(256), dim3(256), 0, stream, x3, pooled);
    hipLaunchKernelGGL(fc_k, dim3(1), dim3(64), 0, stream, pooled, fcw, fcb, out);

    (void)in_sizes; (void)n_in; (void)out_size; (void)ws_size;
}

// Round 4
// 707.766 us; speedup vs baseline: 14.8943x; 1.0693x over previous
//
#include <hip/hip_runtime.h>
#include <math.h>

// eval-mode BatchNorm3d scale: np.float32(1/sqrt(1+1e-5))
#define BN_S 0.9999950000374997f

typedef _Float16 half8 __attribute__((ext_vector_type(8)));
typedef float f32x4 __attribute__((ext_vector_type(4)));

__device__ __forceinline__ float silu_f(float x) {
    return __fdividef(x, 1.0f + __expf(-x));
}

// global -> LDS async DMA, 16B per lane (lane-linear LDS destination)
__device__ __forceinline__ void gld16(const void* g, void* l) {
    __builtin_amdgcn_global_load_lds(
        (const __attribute__((address_space(1))) void*)g,
        (__attribute__((address_space(3))) void*)l, 16, 0, 0);
}

// ---------------------------------------------------------------------------
// Prep: W_mu = mw2 @ uw1, b_mu = mb2 @ uw1 + ub1, and W_em^T = (ew2 @ mw1[64:])^T
// split to fp16 hi/lo in the edge kernel's DMA/frag layout (XOR-swizzled).
// grid(64) block(64): blockIdx = k (K-dim of W_em), thread = c.
// ---------------------------------------------------------------------------
__global__ __launch_bounds__(64) void prep_w_k(
    const float* __restrict__ ew2, const float* __restrict__ mw1,
    const float* __restrict__ mw2, const float* __restrict__ uw1,
    const float* __restrict__ mb2, const float* __restrict__ ub1,
    float* __restrict__ W_mu, float* __restrict__ b_mu,
    _Float16* __restrict__ wemt_h, _Float16* __restrict__ wemt_l)
{
    const int k = blockIdx.x, c = threadIdx.x;
    float s = 0.f;
    for (int m = 0; m < 64; m++) s = fmaf(ew2[k*64 + m], mw1[(64 + m)*64 + c], s);
    // W_em[k][c] = s  ->  A-operand element (m=c, kk=k), swizzled slot layout
    {
        const int q = k >> 5, kg = (k >> 3) & 3, jj = k & 7;
        const int sl = q*256 + c*4 + kg;
        const int p = sl ^ ((sl >> 3) & 7);
        const _Float16 h = (_Float16)s;
        const _Float16 l = (_Float16)(s - (float)h);
        wemt_h[p*8 + jj] = h;
        wemt_l[p*8 + jj] = l;
    }
    float s2 = 0.f;
    for (int m = 0; m < 64; m++) s2 = fmaf(mw2[k*64 + m], uw1[m*64 + c], s2);
    W_mu[k*64 + c] = s2;
    if (k == 0) {
        float s3 = ub1[c];
        for (int m = 0; m < 64; m++) s3 = fmaf(mb2[m], uw1[m*64 + c], s3);
        b_mu[c] = s3;
    }
}

// ---------------------------------------------------------------------------
// Prep per-node / per-voxel tables (unchanged).
// ---------------------------------------------------------------------------
__global__ __launch_bounds__(64) void prep_nodes_k(
    const float* __restrict__ node_embedding, const float* __restrict__ node_pos,
    const float* __restrict__ grid_pos, const float* __restrict__ ew1,
    const float* __restrict__ eb1, const float* __restrict__ mw1,
    const float* __restrict__ mb1, const float* __restrict__ eb2,
    float* __restrict__ a_node, float* __restrict__ g_vox, float* __restrict__ n_node)
{
    const int v = blockIdx.x, c = threadIdx.x;
    const float p0 = node_pos[v*3], p1 = node_pos[v*3 + 1], p2 = node_pos[v*3 + 2];
    a_node[v*64 + c] = fmaf(p0, ew1[c], fmaf(p1, ew1[64 + c], fmaf(p2, ew1[128 + c], eb1[c])));
    const float q0 = grid_pos[v*3], q1 = grid_pos[v*3 + 1], q2 = grid_pos[v*3 + 2];
    g_vox[v*64 + c] = fmaf(q0, ew1[192 + c], fmaf(q1, ew1[256 + c], q2 * ew1[320 + c]));
    float s = mb1[c];
    for (int k = 0; k < 64; k++) s = fmaf(node_embedding[v*64 + k], mw1[k*64 + c], s);
    for (int k = 0; k < 64; k++) s = fmaf(eb2[k], mw1[(64 + k)*64 + c], s);
    n_node[v*64 + c] = s;
}

// ---------------------------------------------------------------------------
// Weight transpose + fp16 hi/lo split into conv DMA layout:
// per (tap, coG, ch): 2048 f16 contiguous = [co64][ci32] with 16B-slot XOR
// swizzle p = s ^ ((s>>3)&7), s = co_local*4 + (ci_local>>3).
// grid(CO, CI/32), block 256.
// ---------------------------------------------------------------------------
template<int K3, int NCOG, int NCH>
__global__ __launch_bounds__(256) void wsplit_k(
    const float* __restrict__ w, _Float16* __restrict__ dh, _Float16* __restrict__ dl,
    int CI)
{
    __shared__ float s[32*K3];
    const int co = blockIdx.x, cig = blockIdx.y, t = threadIdx.x;
    const float* src = w + ((size_t)co*CI + cig*32)*K3;
    for (int m = t; m < 32*K3; m += 256) s[m] = src[m];
    __syncthreads();
    const int coG = co >> 6, col = co & 63;
    for (int m = t; m < 32*K3; m += 256) {
        const int tap = m >> 5, cil = m & 31;
        const float x = s[cil*K3 + tap];
        const _Float16 h = (_Float16)x;
        const _Float16 l = (_Float16)(x - (float)h);
        const int b = cil >> 3, jj = cil & 7;
        const int sl = col*4 + b;
        const int p = sl ^ ((sl >> 3) & 7);
        const size_t base = ((size_t)(tap*NCOG + coG)*NCH + cig) * 2048;
        dh[base + p*8 + jj] = h;
        dl[base + p*8 + jj] = l;
    }
}

// ---------------------------------------------------------------------------
// Edge kernel, MFMA version. One block per voxel j; 4 tiles of 64 edges.
// Phase A: S1 = silu(a_node[i]+g_vox[j]) -> fp16 hi/lo B-tiles in LDS.
// Phase B: H^T = W_em^T @ S1^T via mfma_f32_16x16x32_f16 (3-term split),
// C initialized from gathered n_node; psum += silu(H). Tail MLP as before.
// Output written directly as conv-input fp16 hi/lo split.
// ---------------------------------------------------------------------------
__global__ __launch_bounds__(256) void edge_kernel(
    const int* __restrict__ edge_i,
    const float* __restrict__ a_node, const float* __restrict__ g_vox,
    const float* __restrict__ n_node,
    const _Float16* __restrict__ wemt_h, const _Float16* __restrict__ wemt_l,
    const float* __restrict__ W_mu, const float* __restrict__ b_mu,
    const float* __restrict__ uw2, const float* __restrict__ ub2,
    _Float16* __restrict__ x0h, _Float16* __restrict__ x0l)
{
    __shared__ __align__(16) _Float16 sAh[4096], sAl[4096];   // W_em^T (8KB each)
    __shared__ __align__(16) _Float16 sBh[4096], sBl[4096];   // S1 tile
    __shared__ float sV1[64], sV2[64];

    const int j = blockIdx.x, t = threadIdx.x;
    const int lane = t & 63, wv = t >> 6, ln15 = lane & 15, kg = lane >> 4;
    const int ebase = j << 8;

    // DMA W_em^T (already swizzle-ordered in global)
    gld16(wemt_h + t*8, &sAh[t*8]);
    gld16(wemt_h + 2048 + t*8, &sAh[2048 + t*8]);
    gld16(wemt_l + t*8, &sAl[t*8]);
    gld16(wemt_l + 2048 + t*8, &sAl[2048 + t*8]);

    const int r = t >> 2, sub = t & 3;
    float gv[16];
    #pragma unroll
    for (int m = 0; m < 16; m++) gv[m] = g_vox[j*64 + sub*16 + m];

    asm volatile("s_waitcnt vmcnt(0)" ::: "memory");
    __syncthreads();

    float psum[4] = {0.f, 0.f, 0.f, 0.f};

    for (int T = 0; T < 4; T++) {
        // ---- Phase A: thread (r, sub) computes 16 k-values of edge r ----
        {
            const int i = edge_i[ebase + T*64 + r];
            float s1[16];
            #pragma unroll
            for (int m = 0; m < 16; m++)
                s1[m] = silu_f(a_node[i*64 + sub*16 + m] + gv[m]);
            half8 h0, l0, h1, l1;
            #pragma unroll
            for (int m = 0; m < 8; m++) {
                h0[m] = (_Float16)s1[m];
                l0[m] = (_Float16)(s1[m] - (float)h0[m]);
                h1[m] = (_Float16)s1[8 + m];
                l1[m] = (_Float16)(s1[8 + m] - (float)h1[m]);
            }
            const int q = sub >> 1, kg0 = (sub & 1) * 2;
            const int slot0 = (q*4 + kg0)*64 + r;
            *(half8*)&sBh[slot0*8] = h0; *(half8*)&sBl[slot0*8] = l0;
            *(half8*)&sBh[(slot0 + 64)*8] = h1; *(half8*)&sBl[(slot0 + 64)*8] = l1;
        }
        __syncthreads();
        // ---- Phase B: wave wv owns c-tile wv*16..+15, cols = edges ----
        #pragma unroll
        for (int eF = 0; eF < 4; eF++) {
            const int e = eF*16 + ln15;
            const int ie = edge_i[ebase + T*64 + e];
            f32x4 acc;
            {
                const float4 nv = *(const float4*)&n_node[(size_t)ie*64 + wv*16 + kg*4];
                acc[0] = nv.x; acc[1] = nv.y; acc[2] = nv.z; acc[3] = nv.w;
            }
            #pragma unroll
            for (int q = 0; q < 2; q++) {
                const int sa = q*256 + (wv*16 + ln15)*4 + kg;
                const int pa = sa ^ ((sa >> 3) & 7);
                const half8 Ah = *(const half8*)&sAh[pa*8];
                const half8 Al = *(const half8*)&sAl[pa*8];
                const int sb = ((q*4 + kg)*64 + e)*8;
                const half8 Bh = *(const half8*)&sBh[sb];
                const half8 Bl = *(const half8*)&sBl[sb];
                acc = __builtin_amdgcn_mfma_f32_16x16x32_f16(Ah, Bh, acc, 0, 0, 0);
                acc = __builtin_amdgcn_mfma_f32_16x16x32_f16(Ah, Bl, acc, 0, 0, 0);
                acc = __builtin_amdgcn_mfma_f32_16x16x32_f16(Al, Bh, acc, 0, 0, 0);
            }
            #pragma unroll
            for (int rg = 0; rg < 4; rg++) psum[rg] += silu_f(acc[rg]);
        }
        __syncthreads();   // before next tile overwrites sB
    }

    // sum over the 16 e-columns held across ln15 lanes
    #pragma unroll
    for (int rg = 0; rg < 4; rg++) {
        float v = psum[rg];
        v += __shfl_xor(v, 1, 64); v += __shfl_xor(v, 2, 64);
        v += __shfl_xor(v, 4, 64); v += __shfl_xor(v, 8, 64);
        psum[rg] = v;
    }
    if (ln15 == 0) {
        #pragma unroll
        for (int rg = 0; rg < 4; rg++)
            sV1[wv*16 + kg*4 + rg] = psum[rg] * (1.0f / 256.0f);
    }
    __syncthreads();
    if (t < 64) {
        float h = b_mu[t];
        for (int k = 0; k < 64; k++) h = fmaf(sV1[k], W_mu[k*64 + t], h);
        sV2[t] = silu_f(h);
    }
    __syncthreads();
    if (t < 64) {
        float g = ub2[t];
        for (int k = 0; k < 64; k++) g = fmaf(sV2[k], uw2[k*64 + t], g);
        const float val = g * BN_S;
        const _Float16 hh = (_Float16)val;
        const _Float16 ll = (_Float16)(val - (float)hh);
        const int c = t, zz = j >> 8, v = j & 255;
        const size_t a16 = ((size_t)((c >> 5)*16 + zz)*1024 + ((c >> 3) & 3)*256 + v)*8 + (c & 7);
        x0h[a16] = hh; x0l[a16] = ll;
    }
}

// ---------------------------------------------------------------------------
// Conv3D via MFMA shift-GEMM v3: all staging via global_load_lds DMA.
// Block (d0, coG, kd); 4 waves; wave owns 64co x 64vox of one d-plane.
// X: fp16 hi/lo pre-split, layout [ch][z][oct][vox][8ci] (16KB/chunk, linear).
// W: fp16 hi/lo pre-split+swizzled, 4KB per (tap, coG, ch).
// Counted vmcnt(8) lets X-prefetch stay in flight across taps.
// ---------------------------------------------------------------------------
template<int KK, int CI, int NCOG>
__global__ __launch_bounds__(256) void conv_mfma_k(
    const _Float16* __restrict__ xh, const _Float16* __restrict__ xl,
    const _Float16* __restrict__ wh, const _Float16* __restrict__ wl,
    float* __restrict__ slab)
{
    constexpr int P = KK/2, K2 = KK*KK, NCH = CI/32, CO = NCOG*64;
    const int d0 = blockIdx.x, coG = blockIdx.y, kd = blockIdx.z;
    const int t = threadIdx.x;
    const int lane = t & 63, wv = t >> 6;
    const int ln15 = lane & 15, kg = lane >> 4;

    float* sout = slab + ((size_t)kd*CO + coG*64)*4096 + d0*256;
    const int z = d0 + kd - P;
    if ((unsigned)z >= 16u) {   // OOB depth plane -> zero partial
        for (int m = t; m < 64*256; m += 256)
            sout[(size_t)(m >> 8)*4096 + (m & 255)] = 0.f;
        return;
    }

    __shared__ __align__(16) _Float16 sXh[2][8192];
    __shared__ __align__(16) _Float16 sXl[2][8192];
    __shared__ __align__(16) _Float16 sAh[2][2048];
    __shared__ __align__(16) _Float16 sAl[2][2048];
    __shared__ __align__(16) _Float16 zb[8];
    if (t < 8) zb[t] = (_Float16)0.f;

    auto stage_X = [&](int xb, int ch) {
        const size_t b16 = ((size_t)ch*16 + z) * 8192;
        #pragma unroll
        for (int q = 0; q < 4; q++) {
            gld16(xh + b16 + (q*256 + t)*8, &sXh[xb][(q*256 + t)*8]);
            gld16(xl + b16 + (q*256 + t)*8, &sXl[xb][(q*256 + t)*8]);
        }
    };
    auto stage_A = [&](int ab, int ch, int t2) {
        const size_t b16 = ((size_t)((kd*K2 + t2)*NCOG + coG)*NCH + ch) * 2048;
        gld16(wh + b16 + t*8, &sAh[ab][t*8]);
        gld16(wl + b16 + t*8, &sAl[ab][t*8]);
    };

    f32x4 acc[4][4];
    #pragma unroll
    for (int a = 0; a < 4; a++)
        #pragma unroll
        for (int b = 0; b < 4; b++)
            #pragma unroll
            for (int r2 = 0; r2 < 4; r2++) acc[a][b][r2] = 0.f;

    stage_A(0, 0, 0);
    stage_X(0, 0);
    asm volatile("s_waitcnt vmcnt(0)" ::: "memory");
    __syncthreads();

    int ap = 0;
    for (int ch = 0; ch < NCH; ch++) {
        const int xb = ch & 1;
        for (int t2 = 0; t2 < K2; t2++) {
            bool xpref = false;
            if (t2 + 1 < K2) stage_A(ap ^ 1, ch, t2 + 1);
            else if (ch + 1 < NCH) stage_A(ap ^ 1, ch + 1, 0);
            if (t2 == K2 - 2 && ch + 1 < NCH) { stage_X(xb ^ 1, ch + 1); xpref = true; }

            const int kh = t2 / KK, kw = t2 % KK;
            half8 Afh[4], Afl[4];
            #pragma unroll
            for (int cf = 0; cf < 4; cf++) {
                const int s = (cf*16 + ln15)*4 + kg;
                const int p = s ^ ((s >> 3) & 7);
                Afh[cf] = *(const half8*)&sAh[ap][p*8];
                Afl[cf] = *(const half8*)&sAl[ap][p*8];
            }
            #pragma unroll
            for (int f = 0; f < 4; f++) {
                const int h_in = wv*4 + f + kh - P;
                if ((unsigned)h_in < 16u) {
                    const int w_in = ln15 + kw - P;
                    const bool ok = (unsigned)w_in < 16u;
                    const int slot = ok ? (kg*256 + h_in*16 + w_in) : 0;
                    const half8 Bh = ok ? *(const half8*)&sXh[xb][slot*8] : *(const half8*)zb;
                    const half8 Bl = ok ? *(const half8*)&sXl[xb][slot*8] : *(const half8*)zb;
                    #pragma unroll
                    for (int cf = 0; cf < 4; cf++) {
                        acc[cf][f] = __builtin_amdgcn_mfma_f32_16x16x32_f16(Afh[cf], Bh, acc[cf][f], 0, 0, 0);
                        acc[cf][f] = __builtin_amdgcn_mfma_f32_16x16x32_f16(Afh[cf], Bl, acc[cf][f], 0, 0, 0);
                        acc[cf][f] = __builtin_amdgcn_mfma_f32_16x16x32_f16(Afl[cf], Bh, acc[cf][f], 0, 0, 0);
                    }
                }
            }
            if (xpref) asm volatile("s_waitcnt vmcnt(8)" ::: "memory");
            else       asm volatile("s_waitcnt vmcnt(0)" ::: "memory");
            __syncthreads();
            ap ^= 1;
        }
    }

    // C frag: col=lane&15 (vox), row=(lane>>4)*4+reg (co)
    #pragma unroll
    for (int cf = 0; cf < 4; cf++)
        #pragma unroll
        for (int f = 0; f < 4; f++)
            #pragma unroll
            for (int r2 = 0; r2 < 4; r2++)
                sout[(size_t)(cf*16 + kg*4 + r2)*4096 + wv*64 + f*16 + ln15] = acc[cf][f][r2];
}

// ---------------------------------------------------------------------------
// Reduce S kd-slabs + BN (+residual) (+relu), emit fp32 / fp16-split / poolmax.
// grid(16 z, CO/8); thread = vox-in-plane. Thread owns 8 consecutive channels.
// RMODE: 1 relu, 2 none, 3 add+relu. OUT: 0 fp32, 1 split, 2 poolmax partials.
// ---------------------------------------------------------------------------
template<int S, int RMODE, int OUT>
__global__ __launch_bounds__(256) void reduce_k(
    const float* __restrict__ pbuf, const float* __restrict__ addsrc,
    float* __restrict__ outf, _Float16* __restrict__ oh, _Float16* __restrict__ ol,
    int CO)
{
    const int z = blockIdx.x, c8 = blockIdx.y, v = threadIdx.x;
    float val[8];
    #pragma unroll
    for (int jj = 0; jj < 8; jj++) {
        const int c = c8*8 + jj;
        float a = 0.f;
        #pragma unroll
        for (int s = 0; s < S; s++)
            a += pbuf[((size_t)s*CO + c)*4096 + z*256 + v];
        a *= BN_S;
        if (RMODE == 3) a += addsrc[(size_t)c*4096 + z*256 + v];
        if (RMODE != 2) a = fmaxf(a, 0.f);
        val[jj] = a;
    }
    if (OUT == 0) {
        #pragma unroll
        for (int jj = 0; jj < 8; jj++)
            outf[(size_t)(c8*8 + jj)*4096 + z*256 + v] = val[jj];
    } else if (OUT == 1) {
        half8 hv, lv;
        #pragma unroll
        for (int jj = 0; jj < 8; jj++) {
            hv[jj] = (_Float16)val[jj];
            lv[jj] = (_Float16)(val[jj] - (float)hv[jj]);
        }
        const size_t a16 = ((size_t)((c8 >> 2)*16 + z)*1024 + (c8 & 3)*256 + v)*8;
        *(half8*)&oh[a16] = hv;
        *(half8*)&ol[a16] = lv;
    } else {   // poolmax partials: outf[z*CO + c]
        __shared__ float sm[4][8];
        #pragma unroll
        for (int jj = 0; jj < 8; jj++) {
            float m = val[jj];
            m = fmaxf(m, __shfl_xor(m, 1, 64));  m = fmaxf(m, __shfl_xor(m, 2, 64));
            m = fmaxf(m, __shfl_xor(m, 4, 64));  m = fmaxf(m, __shfl_xor(m, 8, 64));
            m = fmaxf(m, __shfl_xor(m, 16, 64)); m = fmaxf(m, __shfl_xor(m, 32, 64));
            if ((v & 63) == 0) sm[v >> 6][jj] = m;
        }
        __syncthreads();
        if (v < 8) {
            const float m = fmaxf(fmaxf(sm[0][v], sm[1][v]), fmaxf(sm[2][v], sm[3][v]));
            outf[z*CO + c8*8 + v] = m;
        }
    }
}

// ---------------------------------------------------------------------------
// Final: max over 16 z-partials then FC. grid(1), block(256).
// ---------------------------------------------------------------------------
__global__ __launch_bounds__(256) void fc_k(
    const float* __restrict__ pp, const float* __restrict__ fcw,
    const float* __restrict__ fcb, float* __restrict__ out)
{
    __shared__ float sp[256];
    const int t = threadIdx.x;
    float m = pp[t];
    for (int zz = 1; zz < 16; zz++) m = fmaxf(m, pp[zz*256 + t]);
    sp[t] = m;
    __syncthreads();
    if (t < 20) {
        float s = fcb[t];
        for (int c = 0; c < 256; c++) s = fmaf(sp[c], fcw[c*20 + t], s);
        out[t] = s;
    }
}

// ---------------------------------------------------------------------------
extern "C" void kernel_launch(void* const* d_in, const int* in_sizes, int n_in,
                              void* d_out, int out_size, void* d_ws, size_t ws_size,
                              hipStream_t stream)
{
    const float* node_embedding = (const float*)d_in[0];
    const float* node_pos       = (const float*)d_in[1];
    const float* grid_pos       = (const float*)d_in[2];
    const int*   edge_index     = (const int*)d_in[3];
    const float* ew1 = (const float*)d_in[4];
    const float* eb1 = (const float*)d_in[5];
    const float* ew2 = (const float*)d_in[6];
    const float* eb2 = (const float*)d_in[7];
    const float* mw1 = (const float*)d_in[8];
    const float* mb1 = (const float*)d_in[9];
    const float* mw2 = (const float*)d_in[10];
    const float* mb2 = (const float*)d_in[11];
    const float* uw1 = (const float*)d_in[12];
    const float* ub1 = (const float*)d_in[13];
    const float* uw2 = (const float*)d_in[14];
    const float* ub2 = (const float*)d_in[15];
    const float* c1a = (const float*)d_in[16];
    const float* c1b = (const float*)d_in[17];
    const float* c1s = (const float*)d_in[18];
    const float* c2a = (const float*)d_in[19];
    const float* c2b = (const float*)d_in[20];
    const float* c2s = (const float*)d_in[21];
    const float* c3a = (const float*)d_in[22];
    const float* c3b = (const float*)d_in[23];
    const float* c3s = (const float*)d_in[24];
    const float* fcw = (const float*)d_in[25];
    const float* fcb = (const float*)d_in[26];
    float* out = (float*)d_out;
    const int* edge_i = edge_index;   // row 0

    float* ws = (float*)d_ws;
    float* a_node = ws;                ws += 262144;
    float* g_vox  = ws;                ws += 262144;
    float* n_node = ws;                ws += 262144;
    float* W_mu   = ws;                ws += 4096;
    float* b_mu   = ws;                ws += 64;
    _Float16* wemt_h = (_Float16*)ws;  ws += 2048;
    _Float16* wemt_l = (_Float16*)ws;  ws += 2048;
    _Float16* x0h = (_Float16*)ws;     ws += 131072;
    _Float16* x0l = (_Float16*)ws;     ws += 131072;
    _Float16* t2h = (_Float16*)ws;     ws += 262144;
    _Float16* t2l = (_Float16*)ws;     ws += 262144;
    _Float16* x2h = (_Float16*)ws;     ws += 262144;
    _Float16* x2l = (_Float16*)ws;     ws += 262144;
    _Float16* t3h = (_Float16*)ws;     ws += 524288;
    _Float16* t3l = (_Float16*)ws;     ws += 524288;
    float* u2 = ws;                    ws += 524288;
    float* u3 = ws;                    ws += 1048576;
    float* slab = ws;                  ws += 5242880;
    float* poolPart = ws;              ws += 4096;
    _Float16* wh = (_Float16*)ws;      ws += 4585472;   // 9170944 f16
    _Float16* wl = (_Float16*)ws;      ws += 4585472;
    // aliases valid after edge_kernel (node tables dead):
    _Float16* t1h = (_Float16*)a_node;
    _Float16* t1l = (_Float16*)(a_node + 131072);
    float* u1 = g_vox;
    _Float16* x1h = (_Float16*)n_node;
    _Float16* x1l = (_Float16*)(n_node + 131072);

    _Float16* w1a_h = wh + 0;       _Float16* w1a_l = wl + 0;
    _Float16* w1b_h = wh + 110592;  _Float16* w1b_l = wl + 110592;
    _Float16* w1s_h = wh + 221184;  _Float16* w1s_l = wl + 221184;
    _Float16* w2a_h = wh + 733184;  _Float16* w2a_l = wl + 733184;
    _Float16* w2b_h = wh + 954368;  _Float16* w2b_l = wl + 954368;
    _Float16* w2s_h = wh + 1396736; _Float16* w2s_l = wl + 1396736;
    _Float16* w3a_h = wh + 2420736; _Float16* w3a_l = wl + 2420736;
    _Float16* w3b_h = wh + 3305472; _Float16* w3b_l = wl + 3305472;
    _Float16* w3s_h = wh + 5074944; _Float16* w3s_l = wl + 5074944;

    // ---- weight transpose + split ----
    hipLaunchKernelGGL((wsplit_k<27,1,2>),  dim3(64,2),  dim3(256), 0, stream, c1a, w1a_h, w1a_l, 64);
    hipLaunchKernelGGL((wsplit_k<27,1,2>),  dim3(64,2),  dim3(256), 0, stream, c1b, w1b_h, w1b_l, 64);
    hipLaunchKernelGGL((wsplit_k<125,1,2>), dim3(64,2),  dim3(256), 0, stream, c1s, w1s_h, w1s_l, 64);
    hipLaunchKernelGGL((wsplit_k<27,2,2>),  dim3(128,2), dim3(256), 0, stream, c2a, w2a_h, w2a_l, 64);
    hipLaunchKernelGGL((wsplit_k<27,2,4>),  dim3(128,4), dim3(256), 0, stream, c2b, w2b_h, w2b_l, 128);
    hipLaunchKernelGGL((wsplit_k<125,2,2>), dim3(128,2), dim3(256), 0, stream, c2s, w2s_h, w2s_l, 64);
    hipLaunchKernelGGL((wsplit_k<27,4,4>),  dim3(256,4), dim3(256), 0, stream, c3a, w3a_h, w3a_l, 128);
    hipLaunchKernelGGL((wsplit_k<27,4,8>),  dim3(256,8), dim3(256), 0, stream, c3b, w3b_h, w3b_l, 256);
    hipLaunchKernelGGL((wsplit_k<125,4,4>), dim3(256,4), dim3(256), 0, stream, c3s, w3s_h, w3s_l, 128);

    // ---- MPNN ----
    hipLaunchKernelGGL(prep_w_k, dim3(64), dim3(64), 0, stream,
                       ew2, mw1, mw2, uw1, mb2, ub1, W_mu, b_mu, wemt_h, wemt_l);
    hipLaunchKernelGGL(prep_nodes_k, dim3(4096), dim3(64), 0, stream,
                       node_embedding, node_pos, grid_pos, ew1, eb1, mw1, mb1, eb2,
                       a_node, g_vox, n_node);
    hipLaunchKernelGGL(edge_kernel, dim3(4096), dim3(256), 0, stream,
                       edge_i, a_node, g_vox, n_node, wemt_h, wemt_l,
                       W_mu, b_mu, uw2, ub2, x0h, x0l);

    // ---- ResNet3D ----
    // Block 1: 64 -> 64
    hipLaunchKernelGGL((conv_mfma_k<3,64,1>), dim3(16,1,3), dim3(256), 0, stream, x0h, x0l, w1a_h, w1a_l, slab);
    hipLaunchKernelGGL((reduce_k<3,1,1>), dim3(16,8), dim3(256), 0, stream, slab, (const float*)nullptr, (float*)nullptr, t1h, t1l, 64);
    hipLaunchKernelGGL((conv_mfma_k<3,64,1>), dim3(16,1,3), dim3(256), 0, stream, t1h, t1l, w1b_h, w1b_l, slab);
    hipLaunchKernelGGL((reduce_k<3,2,0>), dim3(16,8), dim3(256), 0, stream, slab, (const float*)nullptr, u1, (_Float16*)nullptr, (_Float16*)nullptr, 64);
    hipLaunchKernelGGL((conv_mfma_k<5,64,1>), dim3(16,1,5), dim3(256), 0, stream, x0h, x0l, w1s_h, w1s_l, slab);
    hipLaunchKernelGGL((reduce_k<5,3,1>), dim3(16,8), dim3(256), 0, stream, slab, u1, (float*)nullptr, x1h, x1l, 64);
    // Block 2: 64 -> 128
    hipLaunchKernelGGL((conv_mfma_k<3,64,2>), dim3(16,2,3), dim3(256), 0, stream, x1h, x1l, w2a_h, w2a_l, slab);
    hipLaunchKernelGGL((reduce_k<3,1,1>), dim3(16,16), dim3(256), 0, stream, slab, (const float*)nullptr, (float*)nullptr, t2h, t2l, 128);
    hipLaunchKernelGGL((conv_mfma_k<3,128,2>), dim3(16,2,3), dim3(256), 0, stream, t2h, t2l, w2b_h, w2b_l, slab);
    hipLaunchKernelGGL((reduce_k<3,2,0>), dim3(16,16), dim3(256), 0, stream, slab, (const float*)nullptr, u2, (_Float16*)nullptr, (_Float16*)nullptr, 128);
    hipLaunchKernelGGL((conv_mfma_k<5,64,2>), dim3(16,2,5), dim3(256), 0, stream, x1h, x1l, w2s_h, w2s_l, slab);
    hipLaunchKernelGGL((reduce_k<5,3,1>), dim3(16,16), dim3(256), 0, stream, slab, u2, (float*)nullptr, x2h, x2l, 128);
    // Block 3: 128 -> 256
    hipLaunchKernelGGL((conv_mfma_k<3,128,4>), dim3(16,4,3), dim3(256), 0, stream, x2h, x2l, w3a_h, w3a_l, slab);
    hipLaunchKernelGGL((reduce_k<3,1,1>), dim3(16,32), dim3(256), 0, stream, slab, (const float*)nullptr, (float*)nullptr, t3h, t3l, 256);
    hipLaunchKernelGGL((conv_mfma_k<3,256,4>), dim3(16,4,3), dim3(256), 0, stream, t3h, t3l, w3b_h, w3b_l, slab);
    hipLaunchKernelGGL((reduce_k<3,2,0>), dim3(16,32), dim3(256), 0, stream, slab, (const float*)nullptr, u3, (_Float16*)nullptr, (_Float16*)nullptr, 256);
    hipLaunchKernelGGL((conv_mfma_k<5,128,4>), dim3(16,4,5), dim3(256), 0, stream, x2h, x2l, w3s_h, w3s_l, slab);
    hipLaunchKernelGGL((reduce_k<5,3,2>), dim3(16,32), dim3(256), 0, stream, slab, u3, poolPart, (_Float16*)nullptr, (_Float16*)nullptr, 256);

    hipLaunchKernelGGL(fc_k, dim3(1), dim3(256), 0, stream, poolPart, fcw, fcb, out);

    (void)in_sizes; (void)n_in; (void)out_size; (void)ws_size;
}

// Round 5
// 583.495 us; speedup vs baseline: 18.0665x; 1.2130x over previous
//
#include <hip/hip_runtime.h>
#include <math.h>

// eval-mode BatchNorm3d scale: np.float32(1/sqrt(1+1e-5))
#define BN_S 0.9999950000374997f

typedef _Float16 half8 __attribute__((ext_vector_type(8)));
typedef float f32x4 __attribute__((ext_vector_type(4)));

__device__ __forceinline__ float silu_f(float x) {
    return __fdividef(x, 1.0f + __expf(-x));
}

// global -> LDS async DMA, 16B per lane (lane-linear LDS destination)
__device__ __forceinline__ void gld16(const void* g, void* l) {
    __builtin_amdgcn_global_load_lds(
        (const __attribute__((address_space(1))) void*)g,
        (__attribute__((address_space(3))) void*)l, 16, 0, 0);
}

// ---------------------------------------------------------------------------
// Prep: W_mu = mw2 @ uw1, b_mu = mb2 @ uw1 + ub1, and W_em^T = (ew2 @ mw1[64:])^T
// split to fp16 hi/lo in the edge kernel's DMA/frag layout (XOR-swizzled).
// ---------------------------------------------------------------------------
__global__ __launch_bounds__(64) void prep_w_k(
    const float* __restrict__ ew2, const float* __restrict__ mw1,
    const float* __restrict__ mw2, const float* __restrict__ uw1,
    const float* __restrict__ mb2, const float* __restrict__ ub1,
    float* __restrict__ W_mu, float* __restrict__ b_mu,
    _Float16* __restrict__ wemt_h, _Float16* __restrict__ wemt_l)
{
    const int k = blockIdx.x, c = threadIdx.x;
    float s = 0.f;
    for (int m = 0; m < 64; m++) s = fmaf(ew2[k*64 + m], mw1[(64 + m)*64 + c], s);
    {
        const int q = k >> 5, kg = (k >> 3) & 3, jj = k & 7;
        const int sl = q*256 + c*4 + kg;
        const int p = sl ^ ((sl >> 3) & 7);
        const _Float16 h = (_Float16)s;
        const _Float16 l = (_Float16)(s - (float)h);
        wemt_h[p*8 + jj] = h;
        wemt_l[p*8 + jj] = l;
    }
    float s2 = 0.f;
    for (int m = 0; m < 64; m++) s2 = fmaf(mw2[k*64 + m], uw1[m*64 + c], s2);
    W_mu[k*64 + c] = s2;
    if (k == 0) {
        float s3 = ub1[c];
        for (int m = 0; m < 64; m++) s3 = fmaf(mb2[m], uw1[m*64 + c], s3);
        b_mu[c] = s3;
    }
}

// ---------------------------------------------------------------------------
__global__ __launch_bounds__(64) void prep_nodes_k(
    const float* __restrict__ node_embedding, const float* __restrict__ node_pos,
    const float* __restrict__ grid_pos, const float* __restrict__ ew1,
    const float* __restrict__ eb1, const float* __restrict__ mw1,
    const float* __restrict__ mb1, const float* __restrict__ eb2,
    float* __restrict__ a_node, float* __restrict__ g_vox, float* __restrict__ n_node)
{
    const int v = blockIdx.x, c = threadIdx.x;
    const float p0 = node_pos[v*3], p1 = node_pos[v*3 + 1], p2 = node_pos[v*3 + 2];
    a_node[v*64 + c] = fmaf(p0, ew1[c], fmaf(p1, ew1[64 + c], fmaf(p2, ew1[128 + c], eb1[c])));
    const float q0 = grid_pos[v*3], q1 = grid_pos[v*3 + 1], q2 = grid_pos[v*3 + 2];
    g_vox[v*64 + c] = fmaf(q0, ew1[192 + c], fmaf(q1, ew1[256 + c], q2 * ew1[320 + c]));
    float s = mb1[c];
    for (int k = 0; k < 64; k++) s = fmaf(node_embedding[v*64 + k], mw1[k*64 + c], s);
    for (int k = 0; k < 64; k++) s = fmaf(eb2[k], mw1[(64 + k)*64 + c], s);
    n_node[v*64 + c] = s;
}

// ---------------------------------------------------------------------------
// Weight transpose + fp16 hi/lo split into conv DMA layout (unchanged).
// ---------------------------------------------------------------------------
template<int K3, int NCOG, int NCH>
__global__ __launch_bounds__(256) void wsplit_k(
    const float* __restrict__ w, _Float16* __restrict__ dh, _Float16* __restrict__ dl,
    int CI)
{
    __shared__ float s[32*K3];
    const int co = blockIdx.x, cig = blockIdx.y, t = threadIdx.x;
    const float* src = w + ((size_t)co*CI + cig*32)*K3;
    for (int m = t; m < 32*K3; m += 256) s[m] = src[m];
    __syncthreads();
    const int coG = co >> 6, col = co & 63;
    for (int m = t; m < 32*K3; m += 256) {
        const int tap = m >> 5, cil = m & 31;
        const float x = s[cil*K3 + tap];
        const _Float16 h = (_Float16)x;
        const _Float16 l = (_Float16)(x - (float)h);
        const int b = cil >> 3, jj = cil & 7;
        const int sl = col*4 + b;
        const int p = sl ^ ((sl >> 3) & 7);
        const size_t base = ((size_t)(tap*NCOG + coG)*NCH + cig) * 2048;
        dh[base + p*8 + jj] = h;
        dl[base + p*8 + jj] = l;
    }
}

// ---------------------------------------------------------------------------
// Edge kernel, MFMA version (unchanged from R4 — passed with absmax 0.0).
// ---------------------------------------------------------------------------
__global__ __launch_bounds__(256) void edge_kernel(
    const int* __restrict__ edge_i,
    const float* __restrict__ a_node, const float* __restrict__ g_vox,
    const float* __restrict__ n_node,
    const _Float16* __restrict__ wemt_h, const _Float16* __restrict__ wemt_l,
    const float* __restrict__ W_mu, const float* __restrict__ b_mu,
    const float* __restrict__ uw2, const float* __restrict__ ub2,
    _Float16* __restrict__ x0h, _Float16* __restrict__ x0l)
{
    __shared__ __align__(16) _Float16 sAh[4096], sAl[4096];
    __shared__ __align__(16) _Float16 sBh[4096], sBl[4096];
    __shared__ float sV1[64], sV2[64];

    const int j = blockIdx.x, t = threadIdx.x;
    const int lane = t & 63, wv = t >> 6, ln15 = lane & 15, kg = lane >> 4;
    const int ebase = j << 8;

    gld16(wemt_h + t*8, &sAh[t*8]);
    gld16(wemt_h + 2048 + t*8, &sAh[2048 + t*8]);
    gld16(wemt_l + t*8, &sAl[t*8]);
    gld16(wemt_l + 2048 + t*8, &sAl[2048 + t*8]);

    const int r = t >> 2, sub = t & 3;
    float gv[16];
    #pragma unroll
    for (int m = 0; m < 16; m++) gv[m] = g_vox[j*64 + sub*16 + m];

    asm volatile("s_waitcnt vmcnt(0)" ::: "memory");
    __syncthreads();

    float psum[4] = {0.f, 0.f, 0.f, 0.f};

    for (int T = 0; T < 4; T++) {
        {
            const int i = edge_i[ebase + T*64 + r];
            float s1[16];
            #pragma unroll
            for (int m = 0; m < 16; m++)
                s1[m] = silu_f(a_node[i*64 + sub*16 + m] + gv[m]);
            half8 h0, l0, h1, l1;
            #pragma unroll
            for (int m = 0; m < 8; m++) {
                h0[m] = (_Float16)s1[m];
                l0[m] = (_Float16)(s1[m] - (float)h0[m]);
                h1[m] = (_Float16)s1[8 + m];
                l1[m] = (_Float16)(s1[8 + m] - (float)h1[m]);
            }
            const int q = sub >> 1, kg0 = (sub & 1) * 2;
            const int slot0 = (q*4 + kg0)*64 + r;
            *(half8*)&sBh[slot0*8] = h0; *(half8*)&sBl[slot0*8] = l0;
            *(half8*)&sBh[(slot0 + 64)*8] = h1; *(half8*)&sBl[(slot0 + 64)*8] = l1;
        }
        __syncthreads();
        #pragma unroll
        for (int eF = 0; eF < 4; eF++) {
            const int e = eF*16 + ln15;
            const int ie = edge_i[ebase + T*64 + e];
            f32x4 acc;
            {
                const float4 nv = *(const float4*)&n_node[(size_t)ie*64 + wv*16 + kg*4];
                acc[0] = nv.x; acc[1] = nv.y; acc[2] = nv.z; acc[3] = nv.w;
            }
            #pragma unroll
            for (int q = 0; q < 2; q++) {
                const int sa = q*256 + (wv*16 + ln15)*4 + kg;
                const int pa = sa ^ ((sa >> 3) & 7);
                const half8 Ah = *(const half8*)&sAh[pa*8];
                const half8 Al = *(const half8*)&sAl[pa*8];
                const int sb = ((q*4 + kg)*64 + e)*8;
                const half8 Bh = *(const half8*)&sBh[sb];
                const half8 Bl = *(const half8*)&sBl[sb];
                acc = __builtin_amdgcn_mfma_f32_16x16x32_f16(Ah, Bh, acc, 0, 0, 0);
                acc = __builtin_amdgcn_mfma_f32_16x16x32_f16(Ah, Bl, acc, 0, 0, 0);
                acc = __builtin_amdgcn_mfma_f32_16x16x32_f16(Al, Bh, acc, 0, 0, 0);
            }
            #pragma unroll
            for (int rg = 0; rg < 4; rg++) psum[rg] += silu_f(acc[rg]);
        }
        __syncthreads();
    }

    #pragma unroll
    for (int rg = 0; rg < 4; rg++) {
        float v = psum[rg];
        v += __shfl_xor(v, 1, 64); v += __shfl_xor(v, 2, 64);
        v += __shfl_xor(v, 4, 64); v += __shfl_xor(v, 8, 64);
        psum[rg] = v;
    }
    if (ln15 == 0) {
        #pragma unroll
        for (int rg = 0; rg < 4; rg++)
            sV1[wv*16 + kg*4 + rg] = psum[rg] * (1.0f / 256.0f);
    }
    __syncthreads();
    if (t < 64) {
        float h = b_mu[t];
        for (int k = 0; k < 64; k++) h = fmaf(sV1[k], W_mu[k*64 + t], h);
        sV2[t] = silu_f(h);
    }
    __syncthreads();
    if (t < 64) {
        float g = ub2[t];
        for (int k = 0; k < 64; k++) g = fmaf(sV2[k], uw2[k*64 + t], g);
        const float val = g * BN_S;
        const _Float16 hh = (_Float16)val;
        const _Float16 ll = (_Float16)(val - (float)hh);
        const int c = t, zz = j >> 8, v = j & 255;
        const size_t a16 = ((size_t)((c >> 5)*16 + zz)*1024 + ((c >> 3) & 3)*256 + v)*8 + (c & 7);
        x0h[a16] = hh; x0l[a16] = ll;
    }
}

// ---------------------------------------------------------------------------
// Conv3D via MFMA shift-GEMM v4: single-buffer X (LDS 48KB -> 3 blocks/CU),
// double-buffer A with prefetch-before-compute, optional ci-split (CIS).
// grid(d0=16, coG, z = cis*KK + kd). Slab index = blockIdx.z (S = CIS*KK).
// ---------------------------------------------------------------------------
template<int KK, int CI, int NCOG, int CIS>
__global__ __launch_bounds__(256) void conv_mfma_k(
    const _Float16* __restrict__ xh, const _Float16* __restrict__ xl,
    const _Float16* __restrict__ wh, const _Float16* __restrict__ wl,
    float* __restrict__ slab)
{
    constexpr int P = KK/2, K2 = KK*KK, NCH = CI/32, NCHS = NCH/CIS, CO = NCOG*64;
    const int d0 = blockIdx.x, coG = blockIdx.y;
    const int cis = blockIdx.z / KK, kd = blockIdx.z % KK;
    const int t = threadIdx.x;
    const int lane = t & 63, wv = t >> 6;
    const int ln15 = lane & 15, kg = lane >> 4;

    float* sout = slab + ((size_t)blockIdx.z*CO + coG*64)*4096 + d0*256;
    const int z = d0 + kd - P;
    if ((unsigned)z >= 16u) {   // OOB depth plane -> zero partial
        for (int m = t; m < 64*256; m += 256)
            sout[(size_t)(m >> 8)*4096 + (m & 255)] = 0.f;
        return;
    }

    __shared__ __align__(16) _Float16 sXh[8192];      // 16 KB
    __shared__ __align__(16) _Float16 sXl[8192];      // 16 KB
    __shared__ __align__(16) _Float16 sAh[2][2048];   // 8 KB
    __shared__ __align__(16) _Float16 sAl[2][2048];   // 8 KB
    __shared__ __align__(16) _Float16 zb[8];
    if (t < 8) zb[t] = (_Float16)0.f;

    auto stage_X = [&](int ch) {
        const size_t b16 = ((size_t)ch*16 + z) * 8192;
        #pragma unroll
        for (int q = 0; q < 4; q++) {
            gld16(xh + b16 + (q*256 + t)*8, &sXh[(q*256 + t)*8]);
            gld16(xl + b16 + (q*256 + t)*8, &sXl[(q*256 + t)*8]);
        }
    };
    auto stage_A = [&](int ab, int ch, int t2) {
        const size_t b16 = ((size_t)((kd*K2 + t2)*NCOG + coG)*NCH + ch) * 2048;
        gld16(wh + b16 + t*8, &sAh[ab][t*8]);
        gld16(wl + b16 + t*8, &sAl[ab][t*8]);
    };

    f32x4 acc[4][4];
    #pragma unroll
    for (int a = 0; a < 4; a++)
        #pragma unroll
        for (int b = 0; b < 4; b++)
            #pragma unroll
            for (int r2 = 0; r2 < 4; r2++) acc[a][b][r2] = 0.f;

    const int ch0 = cis * NCHS;
    stage_A(0, ch0, 0);
    stage_X(ch0);
    asm volatile("s_waitcnt vmcnt(0)" ::: "memory");
    __syncthreads();

    int ap = 0;
    for (int cc = 0; cc < NCHS; cc++) {
        const int ch = ch0 + cc;
        for (int t2 = 0; t2 < K2; t2++) {
            // prefetch next tap's weights into the other A buffer
            if (t2 + 1 < K2) stage_A(ap ^ 1, ch, t2 + 1);
            else if (cc + 1 < NCHS) stage_A(ap ^ 1, ch + 1, 0);

            const int kh = t2 / KK, kw = t2 % KK;
            half8 Afh[4], Afl[4];
            #pragma unroll
            for (int cf = 0; cf < 4; cf++) {
                const int s = (cf*16 + ln15)*4 + kg;
                const int p = s ^ ((s >> 3) & 7);
                Afh[cf] = *(const half8*)&sAh[ap][p*8];
                Afl[cf] = *(const half8*)&sAl[ap][p*8];
            }
            __builtin_amdgcn_s_setprio(1);
            #pragma unroll
            for (int f = 0; f < 4; f++) {
                const int h_in = wv*4 + f + kh - P;
                if ((unsigned)h_in < 16u) {
                    const int w_in = ln15 + kw - P;
                    const bool ok = (unsigned)w_in < 16u;
                    const int slot = ok ? (kg*256 + h_in*16 + w_in) : 0;
                    const half8 Bh = ok ? *(const half8*)&sXh[slot*8] : *(const half8*)zb;
                    const half8 Bl = ok ? *(const half8*)&sXl[slot*8] : *(const half8*)zb;
                    #pragma unroll
                    for (int cf = 0; cf < 4; cf++) {
                        acc[cf][f] = __builtin_amdgcn_mfma_f32_16x16x32_f16(Afh[cf], Bh, acc[cf][f], 0, 0, 0);
                        acc[cf][f] = __builtin_amdgcn_mfma_f32_16x16x32_f16(Afh[cf], Bl, acc[cf][f], 0, 0, 0);
                        acc[cf][f] = __builtin_amdgcn_mfma_f32_16x16x32_f16(Afl[cf], Bh, acc[cf][f], 0, 0, 0);
                    }
                }
            }
            __builtin_amdgcn_s_setprio(0);
            if (t2 == K2 - 1) {
                __syncthreads();                   // all waves done reading sX
                if (cc + 1 < NCHS) stage_X(ch + 1);
            }
            asm volatile("s_waitcnt vmcnt(0)" ::: "memory");
            __syncthreads();
            ap ^= 1;
        }
    }

    // C frag: col=lane&15 (vox), row=(lane>>4)*4+reg (co)
    #pragma unroll
    for (int cf = 0; cf < 4; cf++)
        #pragma unroll
        for (int f = 0; f < 4; f++)
            #pragma unroll
            for (int r2 = 0; r2 < 4; r2++)
                sout[(size_t)(cf*16 + kg*4 + r2)*4096 + wv*64 + f*16 + ln15] = acc[cf][f][r2];
}

// ---------------------------------------------------------------------------
// Reduce S kd/cis-slabs + BN (+residual) (+relu); emit fp32 / fp16-split /
// poolmax partials. grid(16 z, CO/8).
// ---------------------------------------------------------------------------
template<int S, int RMODE, int OUT>
__global__ __launch_bounds__(256) void reduce_k(
    const float* __restrict__ pbuf, const float* __restrict__ addsrc,
    float* __restrict__ outf, _Float16* __restrict__ oh, _Float16* __restrict__ ol,
    int CO)
{
    const int z = blockIdx.x, c8 = blockIdx.y, v = threadIdx.x;
    float val[8];
    #pragma unroll
    for (int jj = 0; jj < 8; jj++) {
        const int c = c8*8 + jj;
        float a = 0.f;
        #pragma unroll
        for (int s = 0; s < S; s++)
            a += pbuf[((size_t)s*CO + c)*4096 + z*256 + v];
        a *= BN_S;
        if (RMODE == 3) a += addsrc[(size_t)c*4096 + z*256 + v];
        if (RMODE != 2) a = fmaxf(a, 0.f);
        val[jj] = a;
    }
    if (OUT == 0) {
        #pragma unroll
        for (int jj = 0; jj < 8; jj++)
            outf[(size_t)(c8*8 + jj)*4096 + z*256 + v] = val[jj];
    } else if (OUT == 1) {
        half8 hv, lv;
        #pragma unroll
        for (int jj = 0; jj < 8; jj++) {
            hv[jj] = (_Float16)val[jj];
            lv[jj] = (_Float16)(val[jj] - (float)hv[jj]);
        }
        const size_t a16 = ((size_t)((c8 >> 2)*16 + z)*1024 + (c8 & 3)*256 + v)*8;
        *(half8*)&oh[a16] = hv;
        *(half8*)&ol[a16] = lv;
    } else {
        __shared__ float sm[4][8];
        #pragma unroll
        for (int jj = 0; jj < 8; jj++) {
            float m = val[jj];
            m = fmaxf(m, __shfl_xor(m, 1, 64));  m = fmaxf(m, __shfl_xor(m, 2, 64));
            m = fmaxf(m, __shfl_xor(m, 4, 64));  m = fmaxf(m, __shfl_xor(m, 8, 64));
            m = fmaxf(m, __shfl_xor(m, 16, 64)); m = fmaxf(m, __shfl_xor(m, 32, 64));
            if ((v & 63) == 0) sm[v >> 6][jj] = m;
        }
        __syncthreads();
        if (v < 8) {
            const float m = fmaxf(fmaxf(sm[0][v], sm[1][v]), fmaxf(sm[2][v], sm[3][v]));
            outf[z*CO + c8*8 + v] = m;
        }
    }
}

// ---------------------------------------------------------------------------
__global__ __launch_bounds__(256) void fc_k(
    const float* __restrict__ pp, const float* __restrict__ fcw,
    const float* __restrict__ fcb, float* __restrict__ out)
{
    __shared__ float sp[256];
    const int t = threadIdx.x;
    float m = pp[t];
    for (int zz = 1; zz < 16; zz++) m = fmaxf(m, pp[zz*256 + t]);
    sp[t] = m;
    __syncthreads();
    if (t < 20) {
        float s = fcb[t];
        for (int c = 0; c < 256; c++) s = fmaf(sp[c], fcw[c*20 + t], s);
        out[t] = s;
    }
}

// ---------------------------------------------------------------------------
extern "C" void kernel_launch(void* const* d_in, const int* in_sizes, int n_in,
                              void* d_out, int out_size, void* d_ws, size_t ws_size,
                              hipStream_t stream)
{
    const float* node_embedding = (const float*)d_in[0];
    const float* node_pos       = (const float*)d_in[1];
    const float* grid_pos       = (const float*)d_in[2];
    const int*   edge_index     = (const int*)d_in[3];
    const float* ew1 = (const float*)d_in[4];
    const float* eb1 = (const float*)d_in[5];
    const float* ew2 = (const float*)d_in[6];
    const float* eb2 = (const float*)d_in[7];
    const float* mw1 = (const float*)d_in[8];
    const float* mb1 = (const float*)d_in[9];
    const float* mw2 = (const float*)d_in[10];
    const float* mb2 = (const float*)d_in[11];
    const float* uw1 = (const float*)d_in[12];
    const float* ub1 = (const float*)d_in[13];
    const float* uw2 = (const float*)d_in[14];
    const float* ub2 = (const float*)d_in[15];
    const float* c1a = (const float*)d_in[16];
    const float* c1b = (const float*)d_in[17];
    const float* c1s = (const float*)d_in[18];
    const float* c2a = (const float*)d_in[19];
    const float* c2b = (const float*)d_in[20];
    const float* c2s = (const float*)d_in[21];
    const float* c3a = (const float*)d_in[22];
    const float* c3b = (const float*)d_in[23];
    const float* c3s = (const float*)d_in[24];
    const float* fcw = (const float*)d_in[25];
    const float* fcb = (const float*)d_in[26];
    float* out = (float*)d_out;
    const int* edge_i = edge_index;   // row 0

    float* ws = (float*)d_ws;
    float* a_node = ws;                ws += 262144;
    float* g_vox  = ws;                ws += 262144;
    float* n_node = ws;                ws += 262144;
    float* W_mu   = ws;                ws += 4096;
    float* b_mu   = ws;                ws += 64;
    _Float16* wemt_h = (_Float16*)ws;  ws += 2048;
    _Float16* wemt_l = (_Float16*)ws;  ws += 2048;
    _Float16* x0h = (_Float16*)ws;     ws += 131072;
    _Float16* x0l = (_Float16*)ws;     ws += 131072;
    _Float16* t2h = (_Float16*)ws;     ws += 262144;
    _Float16* t2l = (_Float16*)ws;     ws += 262144;
    _Float16* x2h = (_Float16*)ws;     ws += 262144;
    _Float16* x2l = (_Float16*)ws;     ws += 262144;
    _Float16* t3h = (_Float16*)ws;     ws += 524288;
    _Float16* t3l = (_Float16*)ws;     ws += 524288;
    float* u2 = ws;                    ws += 524288;
    float* u3 = ws;                    ws += 1048576;
    float* slab = ws;                  ws += 5242880;
    float* poolPart = ws;              ws += 4096;
    _Float16* wh = (_Float16*)ws;      ws += 4585472;   // 9170944 f16
    _Float16* wl = (_Float16*)ws;      ws += 4585472;
    // aliases valid after edge_kernel (node tables dead):
    _Float16* t1h = (_Float16*)a_node;
    _Float16* t1l = (_Float16*)(a_node + 131072);
    float* u1 = g_vox;
    _Float16* x1h = (_Float16*)n_node;
    _Float16* x1l = (_Float16*)(n_node + 131072);

    _Float16* w1a_h = wh + 0;       _Float16* w1a_l = wl + 0;
    _Float16* w1b_h = wh + 110592;  _Float16* w1b_l = wl + 110592;
    _Float16* w1s_h = wh + 221184;  _Float16* w1s_l = wl + 221184;
    _Float16* w2a_h = wh + 733184;  _Float16* w2a_l = wl + 733184;
    _Float16* w2b_h = wh + 954368;  _Float16* w2b_l = wl + 954368;
    _Float16* w2s_h = wh + 1396736; _Float16* w2s_l = wl + 1396736;
    _Float16* w3a_h = wh + 2420736; _Float16* w3a_l = wl + 2420736;
    _Float16* w3b_h = wh + 3305472; _Float16* w3b_l = wl + 3305472;
    _Float16* w3s_h = wh + 5074944; _Float16* w3s_l = wl + 5074944;

    // ---- weight transpose + split ----
    hipLaunchKernelGGL((wsplit_k<27,1,2>),  dim3(64,2),  dim3(256), 0, stream, c1a, w1a_h, w1a_l, 64);
    hipLaunchKernelGGL((wsplit_k<27,1,2>),  dim3(64,2),  dim3(256), 0, stream, c1b, w1b_h, w1b_l, 64);
    hipLaunchKernelGGL((wsplit_k<125,1,2>), dim3(64,2),  dim3(256), 0, stream, c1s, w1s_h, w1s_l, 64);
    hipLaunchKernelGGL((wsplit_k<27,2,2>),  dim3(128,2), dim3(256), 0, stream, c2a, w2a_h, w2a_l, 64);
    hipLaunchKernelGGL((wsplit_k<27,2,4>),  dim3(128,4), dim3(256), 0, stream, c2b, w2b_h, w2b_l, 128);
    hipLaunchKernelGGL((wsplit_k<125,2,2>), dim3(128,2), dim3(256), 0, stream, c2s, w2s_h, w2s_l, 64);
    hipLaunchKernelGGL((wsplit_k<27,4,4>),  dim3(256,4), dim3(256), 0, stream, c3a, w3a_h, w3a_l, 128);
    hipLaunchKernelGGL((wsplit_k<27,4,8>),  dim3(256,8), dim3(256), 0, stream, c3b, w3b_h, w3b_l, 256);
    hipLaunchKernelGGL((wsplit_k<125,4,4>), dim3(256,4), dim3(256), 0, stream, c3s, w3s_h, w3s_l, 128);

    // ---- MPNN ----
    hipLaunchKernelGGL(prep_w_k, dim3(64), dim3(64), 0, stream,
                       ew2, mw1, mw2, uw1, mb2, ub1, W_mu, b_mu, wemt_h, wemt_l);
    hipLaunchKernelGGL(prep_nodes_k, dim3(4096), dim3(64), 0, stream,
                       node_embedding, node_pos, grid_pos, ew1, eb1, mw1, mb1, eb2,
                       a_node, g_vox, n_node);
    hipLaunchKernelGGL(edge_kernel, dim3(4096), dim3(256), 0, stream,
                       edge_i, a_node, g_vox, n_node, wemt_h, wemt_l,
                       W_mu, b_mu, uw2, ub2, x0h, x0l);

    // ---- ResNet3D ----
    // Block 1: 64 -> 64  (ci-split 2: S = 2*KK slabs)
    hipLaunchKernelGGL((conv_mfma_k<3,64,1,2>), dim3(16,1,6), dim3(256), 0, stream, x0h, x0l, w1a_h, w1a_l, slab);
    hipLaunchKernelGGL((reduce_k<6,1,1>), dim3(16,8), dim3(256), 0, stream, slab, (const float*)nullptr, (float*)nullptr, t1h, t1l, 64);
    hipLaunchKernelGGL((conv_mfma_k<3,64,1,2>), dim3(16,1,6), dim3(256), 0, stream, t1h, t1l, w1b_h, w1b_l, slab);
    hipLaunchKernelGGL((reduce_k<6,2,0>), dim3(16,8), dim3(256), 0, stream, slab, (const float*)nullptr, u1, (_Float16*)nullptr, (_Float16*)nullptr, 64);
    hipLaunchKernelGGL((conv_mfma_k<5,64,1,2>), dim3(16,1,10), dim3(256), 0, stream, x0h, x0l, w1s_h, w1s_l, slab);
    hipLaunchKernelGGL((reduce_k<10,3,1>), dim3(16,8), dim3(256), 0, stream, slab, u1, (float*)nullptr, x1h, x1l, 64);
    // Block 2: 64 -> 128
    hipLaunchKernelGGL((conv_mfma_k<3,64,2,2>), dim3(16,2,6), dim3(256), 0, stream, x1h, x1l, w2a_h, w2a_l, slab);
    hipLaunchKernelGGL((reduce_k<6,1,1>), dim3(16,16), dim3(256), 0, stream, slab, (const float*)nullptr, (float*)nullptr, t2h, t2l, 128);
    hipLaunchKernelGGL((conv_mfma_k<3,128,2,2>), dim3(16,2,6), dim3(256), 0, stream, t2h, t2l, w2b_h, w2b_l, slab);
    hipLaunchKernelGGL((reduce_k<6,2,0>), dim3(16,16), dim3(256), 0, stream, slab, (const float*)nullptr, u2, (_Float16*)nullptr, (_Float16*)nullptr, 128);
    hipLaunchKernelGGL((conv_mfma_k<5,64,2,2>), dim3(16,2,10), dim3(256), 0, stream, x1h, x1l, w2s_h, w2s_l, slab);
    hipLaunchKernelGGL((reduce_k<10,3,1>), dim3(16,16), dim3(256), 0, stream, slab, u2, (float*)nullptr, x2h, x2l, 128);
    // Block 3: 128 -> 256  (no ci-split: slab budget)
    hipLaunchKernelGGL((conv_mfma_k<3,128,4,1>), dim3(16,4,3), dim3(256), 0, stream, x2h, x2l, w3a_h, w3a_l, slab);
    hipLaunchKernelGGL((reduce_k<3,1,1>), dim3(16,32), dim3(256), 0, stream, slab, (const float*)nullptr, (float*)nullptr, t3h, t3l, 256);
    hipLaunchKernelGGL((conv_mfma_k<3,256,4,1>), dim3(16,4,3), dim3(256), 0, stream, t3h, t3l, w3b_h, w3b_l, slab);
    hipLaunchKernelGGL((reduce_k<3,2,0>), dim3(16,32), dim3(256), 0, stream, slab, (const float*)nullptr, u3, (_Float16*)nullptr, (_Float16*)nullptr, 256);
    hipLaunchKernelGGL((conv_mfma_k<5,128,4,1>), dim3(16,4,5), dim3(256), 0, stream, x2h, x2l, w3s_h, w3s_l, slab);
    hipLaunchKernelGGL((reduce_k<5,3,2>), dim3(16,32), dim3(256), 0, stream, slab, u3, poolPart, (_Float16*)nullptr, (_Float16*)nullptr, 256);

    hipLaunchKernelGGL(fc_k, dim3(1), dim3(256), 0, stream, poolPart, fcw, fcb, out);

    (void)in_sizes; (void)n_in; (void)out_size; (void)ws_size;
}

// Round 6
// 529.748 us; speedup vs baseline: 19.8995x; 1.1015x over previous
//
#include <hip/hip_runtime.h>
#include <math.h>

// eval-mode BatchNorm3d scale: np.float32(1/sqrt(1+1e-5))
#define BN_S 0.9999950000374997f

typedef _Float16 half8 __attribute__((ext_vector_type(8)));
typedef float f32x4 __attribute__((ext_vector_type(4)));

__device__ __forceinline__ float silu_f(float x) {
    return __fdividef(x, 1.0f + __expf(-x));
}

// global -> LDS async DMA, 16B per lane (lane-linear LDS destination)
__device__ __forceinline__ void gld16(const void* g, void* l) {
    __builtin_amdgcn_global_load_lds(
        (const __attribute__((address_space(1))) void*)g,
        (__attribute__((address_space(3))) void*)l, 16, 0, 0);
}

// ---------------------------------------------------------------------------
// Prep: W_mu = mw2 @ uw1, b_mu = mb2 @ uw1 + ub1, and W_em^T = (ew2 @ mw1[64:])^T
// split to fp16 hi/lo in the edge kernel's DMA/frag layout (XOR-swizzled).
// ---------------------------------------------------------------------------
__global__ __launch_bounds__(64) void prep_w_k(
    const float* __restrict__ ew2, const float* __restrict__ mw1,
    const float* __restrict__ mw2, const float* __restrict__ uw1,
    const float* __restrict__ mb2, const float* __restrict__ ub1,
    float* __restrict__ W_mu, float* __restrict__ b_mu,
    _Float16* __restrict__ wemt_h, _Float16* __restrict__ wemt_l)
{
    const int k = blockIdx.x, c = threadIdx.x;
    float s = 0.f;
    for (int m = 0; m < 64; m++) s = fmaf(ew2[k*64 + m], mw1[(64 + m)*64 + c], s);
    {
        const int q = k >> 5, kg = (k >> 3) & 3, jj = k & 7;
        const int sl = q*256 + c*4 + kg;
        const int p = sl ^ ((sl >> 3) & 7);
        const _Float16 h = (_Float16)s;
        const _Float16 l = (_Float16)(s - (float)h);
        wemt_h[p*8 + jj] = h;
        wemt_l[p*8 + jj] = l;
    }
    float s2 = 0.f;
    for (int m = 0; m < 64; m++) s2 = fmaf(mw2[k*64 + m], uw1[m*64 + c], s2);
    W_mu[k*64 + c] = s2;
    if (k == 0) {
        float s3 = ub1[c];
        for (int m = 0; m < 64; m++) s3 = fmaf(mb2[m], uw1[m*64 + c], s3);
        b_mu[c] = s3;
    }
}

// ---------------------------------------------------------------------------
__global__ __launch_bounds__(64) void prep_nodes_k(
    const float* __restrict__ node_embedding, const float* __restrict__ node_pos,
    const float* __restrict__ grid_pos, const float* __restrict__ ew1,
    const float* __restrict__ eb1, const float* __restrict__ mw1,
    const float* __restrict__ mb1, const float* __restrict__ eb2,
    float* __restrict__ a_node, float* __restrict__ g_vox, float* __restrict__ n_node)
{
    const int v = blockIdx.x, c = threadIdx.x;
    const float p0 = node_pos[v*3], p1 = node_pos[v*3 + 1], p2 = node_pos[v*3 + 2];
    a_node[v*64 + c] = fmaf(p0, ew1[c], fmaf(p1, ew1[64 + c], fmaf(p2, ew1[128 + c], eb1[c])));
    const float q0 = grid_pos[v*3], q1 = grid_pos[v*3 + 1], q2 = grid_pos[v*3 + 2];
    g_vox[v*64 + c] = fmaf(q0, ew1[192 + c], fmaf(q1, ew1[256 + c], q2 * ew1[320 + c]));
    float s = mb1[c];
    for (int k = 0; k < 64; k++) s = fmaf(node_embedding[v*64 + k], mw1[k*64 + c], s);
    for (int k = 0; k < 64; k++) s = fmaf(eb2[k], mw1[(64 + k)*64 + c], s);
    n_node[v*64 + c] = s;
}

// ---------------------------------------------------------------------------
// Weight transpose + fp16 hi/lo split into conv layout (unchanged):
// per (tap, coG, ch): 2048 f16 = [co64][ci32] with 16B-slot XOR swizzle.
// ---------------------------------------------------------------------------
template<int K3, int NCOG, int NCH>
__global__ __launch_bounds__(256) void wsplit_k(
    const float* __restrict__ w, _Float16* __restrict__ dh, _Float16* __restrict__ dl,
    int CI)
{
    __shared__ float s[32*K3];
    const int co = blockIdx.x, cig = blockIdx.y, t = threadIdx.x;
    const float* src = w + ((size_t)co*CI + cig*32)*K3;
    for (int m = t; m < 32*K3; m += 256) s[m] = src[m];
    __syncthreads();
    const int coG = co >> 6, col = co & 63;
    for (int m = t; m < 32*K3; m += 256) {
        const int tap = m >> 5, cil = m & 31;
        const float x = s[cil*K3 + tap];
        const _Float16 h = (_Float16)x;
        const _Float16 l = (_Float16)(x - (float)h);
        const int b = cil >> 3, jj = cil & 7;
        const int sl = col*4 + b;
        const int p = sl ^ ((sl >> 3) & 7);
        const size_t base = ((size_t)(tap*NCOG + coG)*NCH + cig) * 2048;
        dh[base + p*8 + jj] = h;
        dl[base + p*8 + jj] = l;
    }
}

// ---------------------------------------------------------------------------
// Edge kernel, MFMA version (unchanged — passed with absmax 0.0).
// ---------------------------------------------------------------------------
__global__ __launch_bounds__(256) void edge_kernel(
    const int* __restrict__ edge_i,
    const float* __restrict__ a_node, const float* __restrict__ g_vox,
    const float* __restrict__ n_node,
    const _Float16* __restrict__ wemt_h, const _Float16* __restrict__ wemt_l,
    const float* __restrict__ W_mu, const float* __restrict__ b_mu,
    const float* __restrict__ uw2, const float* __restrict__ ub2,
    _Float16* __restrict__ x0h, _Float16* __restrict__ x0l)
{
    __shared__ __align__(16) _Float16 sAh[4096], sAl[4096];
    __shared__ __align__(16) _Float16 sBh[4096], sBl[4096];
    __shared__ float sV1[64], sV2[64];

    const int j = blockIdx.x, t = threadIdx.x;
    const int lane = t & 63, wv = t >> 6, ln15 = lane & 15, kg = lane >> 4;
    const int ebase = j << 8;

    gld16(wemt_h + t*8, &sAh[t*8]);
    gld16(wemt_h + 2048 + t*8, &sAh[2048 + t*8]);
    gld16(wemt_l + t*8, &sAl[t*8]);
    gld16(wemt_l + 2048 + t*8, &sAl[2048 + t*8]);

    const int r = t >> 2, sub = t & 3;
    float gv[16];
    #pragma unroll
    for (int m = 0; m < 16; m++) gv[m] = g_vox[j*64 + sub*16 + m];

    asm volatile("s_waitcnt vmcnt(0)" ::: "memory");
    __syncthreads();

    float psum[4] = {0.f, 0.f, 0.f, 0.f};

    for (int T = 0; T < 4; T++) {
        {
            const int i = edge_i[ebase + T*64 + r];
            float s1[16];
            #pragma unroll
            for (int m = 0; m < 16; m++)
                s1[m] = silu_f(a_node[i*64 + sub*16 + m] + gv[m]);
            half8 h0, l0, h1, l1;
            #pragma unroll
            for (int m = 0; m < 8; m++) {
                h0[m] = (_Float16)s1[m];
                l0[m] = (_Float16)(s1[m] - (float)h0[m]);
                h1[m] = (_Float16)s1[8 + m];
                l1[m] = (_Float16)(s1[8 + m] - (float)h1[m]);
            }
            const int q = sub >> 1, kg0 = (sub & 1) * 2;
            const int slot0 = (q*4 + kg0)*64 + r;
            *(half8*)&sBh[slot0*8] = h0; *(half8*)&sBl[slot0*8] = l0;
            *(half8*)&sBh[(slot0 + 64)*8] = h1; *(half8*)&sBl[(slot0 + 64)*8] = l1;
        }
        __syncthreads();
        #pragma unroll
        for (int eF = 0; eF < 4; eF++) {
            const int e = eF*16 + ln15;
            const int ie = edge_i[ebase + T*64 + e];
            f32x4 acc;
            {
                const float4 nv = *(const float4*)&n_node[(size_t)ie*64 + wv*16 + kg*4];
                acc[0] = nv.x; acc[1] = nv.y; acc[2] = nv.z; acc[3] = nv.w;
            }
            #pragma unroll
            for (int q = 0; q < 2; q++) {
                const int sa = q*256 + (wv*16 + ln15)*4 + kg;
                const int pa = sa ^ ((sa >> 3) & 7);
                const half8 Ah = *(const half8*)&sAh[pa*8];
                const half8 Al = *(const half8*)&sAl[pa*8];
                const int sb = ((q*4 + kg)*64 + e)*8;
                const half8 Bh = *(const half8*)&sBh[sb];
                const half8 Bl = *(const half8*)&sBl[sb];
                acc = __builtin_amdgcn_mfma_f32_16x16x32_f16(Ah, Bh, acc, 0, 0, 0);
                acc = __builtin_amdgcn_mfma_f32_16x16x32_f16(Ah, Bl, acc, 0, 0, 0);
                acc = __builtin_amdgcn_mfma_f32_16x16x32_f16(Al, Bh, acc, 0, 0, 0);
            }
            #pragma unroll
            for (int rg = 0; rg < 4; rg++) psum[rg] += silu_f(acc[rg]);
        }
        __syncthreads();
    }

    #pragma unroll
    for (int rg = 0; rg < 4; rg++) {
        float v = psum[rg];
        v += __shfl_xor(v, 1, 64); v += __shfl_xor(v, 2, 64);
        v += __shfl_xor(v, 4, 64); v += __shfl_xor(v, 8, 64);
        psum[rg] = v;
    }
    if (ln15 == 0) {
        #pragma unroll
        for (int rg = 0; rg < 4; rg++)
            sV1[wv*16 + kg*4 + rg] = psum[rg] * (1.0f / 256.0f);
    }
    __syncthreads();
    if (t < 64) {
        float h = b_mu[t];
        for (int k = 0; k < 64; k++) h = fmaf(sV1[k], W_mu[k*64 + t], h);
        sV2[t] = silu_f(h);
    }
    __syncthreads();
    if (t < 64) {
        float g = ub2[t];
        for (int k = 0; k < 64; k++) g = fmaf(sV2[k], uw2[k*64 + t], g);
        const float val = g * BN_S;
        const _Float16 hh = (_Float16)val;
        const _Float16 ll = (_Float16)(val - (float)hh);
        const int c = t, zz = j >> 8, v = j & 255;
        const size_t a16 = ((size_t)((c >> 5)*16 + zz)*1024 + ((c >> 3) & 3)*256 + v)*8 + (c & 7);
        x0h[a16] = hh; x0l[a16] = ll;
    }
}

// ---------------------------------------------------------------------------
// Conv3D via MFMA shift-GEMM v5:
//  - A (weights): per-wave REGISTER loads from global (swizzled layout),
//    software-prefetched one tap ahead -> zero per-tap barriers/drains.
//  - X: LDS double-buffer via global_load_lds; ONE barrier per 32-ci chunk;
//    next-chunk DMA issued at chunk start (early-drain ~1 tap in, amortized).
// grid(d0=16, coG, z = cis*KK + kd); slab index = blockIdx.z; S = CIS*KK.
// ---------------------------------------------------------------------------
template<int KK, int CI, int NCOG, int CIS>
__global__ __launch_bounds__(256) void conv_mfma_k(
    const _Float16* __restrict__ xh, const _Float16* __restrict__ xl,
    const _Float16* __restrict__ wh, const _Float16* __restrict__ wl,
    float* __restrict__ slab)
{
    constexpr int P = KK/2, K2 = KK*KK, NCH = CI/32, NCHS = NCH/CIS, CO = NCOG*64;
    const int d0 = blockIdx.x, coG = blockIdx.y;
    const int cis = blockIdx.z / KK, kd = blockIdx.z % KK;
    const int t = threadIdx.x;
    const int lane = t & 63, wv = t >> 6;
    const int ln15 = lane & 15, kg = lane >> 4;

    float* sout = slab + ((size_t)blockIdx.z*CO + coG*64)*4096 + d0*256;
    const int z = d0 + kd - P;
    if ((unsigned)z >= 16u) {   // OOB depth plane -> zero partial
        for (int m = t; m < 64*256; m += 256)
            sout[(size_t)(m >> 8)*4096 + (m & 255)] = 0.f;
        return;
    }

    __shared__ __align__(16) _Float16 sXh[2][8192];   // 32 KB
    __shared__ __align__(16) _Float16 sXl[2][8192];   // 32 KB
    __shared__ __align__(16) _Float16 zb[8];
    if (t < 8) zb[t] = (_Float16)0.f;

    // per-lane A fragment offsets (swizzled), constant across taps
    int aoff[4];
    #pragma unroll
    for (int cf = 0; cf < 4; cf++) {
        const int s = (cf*16 + ln15)*4 + kg;
        aoff[cf] = (s ^ ((s >> 3) & 7)) * 8;
    }

    auto stage_X = [&](int xb, int ch) {
        const size_t b16 = ((size_t)ch*16 + z) * 8192;
        #pragma unroll
        for (int q = 0; q < 4; q++) {
            gld16(xh + b16 + (q*256 + t)*8, &sXh[xb][(q*256 + t)*8]);
            gld16(xl + b16 + (q*256 + t)*8, &sXl[xb][(q*256 + t)*8]);
        }
    };
    auto loadA = [&](int ch, int t2, half8* Ah, half8* Al) {
        const size_t b = ((size_t)((kd*K2 + t2)*NCOG + coG)*NCH + ch) * 2048;
        #pragma unroll
        for (int cf = 0; cf < 4; cf++) {
            Ah[cf] = *(const half8*)&wh[b + aoff[cf]];
            Al[cf] = *(const half8*)&wl[b + aoff[cf]];
        }
    };

    f32x4 acc[4][4];
    #pragma unroll
    for (int a = 0; a < 4; a++)
        #pragma unroll
        for (int b = 0; b < 4; b++)
            #pragma unroll
            for (int r2 = 0; r2 < 4; r2++) acc[a][b][r2] = 0.f;

    const int ch0 = cis * NCHS;
    half8 nAh[4], nAl[4];
    stage_X(0, ch0);
    loadA(ch0, 0, nAh, nAl);
    asm volatile("s_waitcnt vmcnt(0)" ::: "memory");
    __syncthreads();

    for (int cc = 0; cc < NCHS; cc++) {
        const int ch = ch0 + cc, xb = cc & 1;
        if (cc + 1 < NCHS) stage_X(xb ^ 1, ch + 1);   // DMA flies across the chunk
        for (int t2 = 0; t2 < K2; t2++) {
            half8 cAh[4], cAl[4];
            #pragma unroll
            for (int cf = 0; cf < 4; cf++) { cAh[cf] = nAh[cf]; cAl[cf] = nAl[cf]; }
            if (t2 + 1 < K2)          loadA(ch, t2 + 1, nAh, nAl);
            else if (cc + 1 < NCHS)   loadA(ch + 1, 0, nAh, nAl);

            const int kh = t2 / KK, kw = t2 % KK;
            __builtin_amdgcn_s_setprio(1);
            #pragma unroll
            for (int f = 0; f < 4; f++) {
                const int h_in = wv*4 + f + kh - P;
                if ((unsigned)h_in < 16u) {
                    const int w_in = ln15 + kw - P;
                    const bool ok = (unsigned)w_in < 16u;
                    const int slot = ok ? (kg*256 + h_in*16 + w_in) : 0;
                    const half8 Bh = ok ? *(const half8*)&sXh[xb][slot*8] : *(const half8*)zb;
                    const half8 Bl = ok ? *(const half8*)&sXl[xb][slot*8] : *(const half8*)zb;
                    #pragma unroll
                    for (int cf = 0; cf < 4; cf++) {
                        acc[cf][f] = __builtin_amdgcn_mfma_f32_16x16x32_f16(cAh[cf], Bh, acc[cf][f], 0, 0, 0);
                        acc[cf][f] = __builtin_amdgcn_mfma_f32_16x16x32_f16(cAh[cf], Bl, acc[cf][f], 0, 0, 0);
                        acc[cf][f] = __builtin_amdgcn_mfma_f32_16x16x32_f16(cAl[cf], Bh, acc[cf][f], 0, 0, 0);
                    }
                }
            }
            __builtin_amdgcn_s_setprio(0);
        }
        __syncthreads();   // all waves done reading sX[xb]; next chunk flips buffers
    }

    // C frag: col=lane&15 (vox), row=(lane>>4)*4+reg (co)
    #pragma unroll
    for (int cf = 0; cf < 4; cf++)
        #pragma unroll
        for (int f = 0; f < 4; f++)
            #pragma unroll
            for (int r2 = 0; r2 < 4; r2++)
                sout[(size_t)(cf*16 + kg*4 + r2)*4096 + wv*64 + f*16 + ln15] = acc[cf][f][r2];
}

// ---------------------------------------------------------------------------
// Reduce S kd/cis-slabs + BN (+residual) (+relu); emit fp32 / fp16-split /
// poolmax partials. grid(16 z, CO/8).
// ---------------------------------------------------------------------------
template<int S, int RMODE, int OUT>
__global__ __launch_bounds__(256) void reduce_k(
    const float* __restrict__ pbuf, const float* __restrict__ addsrc,
    float* __restrict__ outf, _Float16* __restrict__ oh, _Float16* __restrict__ ol,
    int CO)
{
    const int z = blockIdx.x, c8 = blockIdx.y, v = threadIdx.x;
    float val[8];
    #pragma unroll
    for (int jj = 0; jj < 8; jj++) {
        const int c = c8*8 + jj;
        float a = 0.f;
        #pragma unroll
        for (int s = 0; s < S; s++)
            a += pbuf[((size_t)s*CO + c)*4096 + z*256 + v];
        a *= BN_S;
        if (RMODE == 3) a += addsrc[(size_t)c*4096 + z*256 + v];
        if (RMODE != 2) a = fmaxf(a, 0.f);
        val[jj] = a;
    }
    if (OUT == 0) {
        #pragma unroll
        for (int jj = 0; jj < 8; jj++)
            outf[(size_t)(c8*8 + jj)*4096 + z*256 + v] = val[jj];
    } else if (OUT == 1) {
        half8 hv, lv;
        #pragma unroll
        for (int jj = 0; jj < 8; jj++) {
            hv[jj] = (_Float16)val[jj];
            lv[jj] = (_Float16)(val[jj] - (float)hv[jj]);
        }
        const size_t a16 = ((size_t)((c8 >> 2)*16 + z)*1024 + (c8 & 3)*256 + v)*8;
        *(half8*)&oh[a16] = hv;
        *(half8*)&ol[a16] = lv;
    } else {
        __shared__ float sm[4][8];
        #pragma unroll
        for (int jj = 0; jj < 8; jj++) {
            float m = val[jj];
            m = fmaxf(m, __shfl_xor(m, 1, 64));  m = fmaxf(m, __shfl_xor(m, 2, 64));
            m = fmaxf(m, __shfl_xor(m, 4, 64));  m = fmaxf(m, __shfl_xor(m, 8, 64));
            m = fmaxf(m, __shfl_xor(m, 16, 64)); m = fmaxf(m, __shfl_xor(m, 32, 64));
            if ((v & 63) == 0) sm[v >> 6][jj] = m;
        }
        __syncthreads();
        if (v < 8) {
            const float m = fmaxf(fmaxf(sm[0][v], sm[1][v]), fmaxf(sm[2][v], sm[3][v]));
            outf[z*CO + c8*8 + v] = m;
        }
    }
}

// ---------------------------------------------------------------------------
__global__ __launch_bounds__(256) void fc_k(
    const float* __restrict__ pp, const float* __restrict__ fcw,
    const float* __restrict__ fcb, float* __restrict__ out)
{
    __shared__ float sp[256];
    const int t = threadIdx.x;
    float m = pp[t];
    for (int zz = 1; zz < 16; zz++) m = fmaxf(m, pp[zz*256 + t]);
    sp[t] = m;
    __syncthreads();
    if (t < 20) {
        float s = fcb[t];
        for (int c = 0; c < 256; c++) s = fmaf(sp[c], fcw[c*20 + t], s);
        out[t] = s;
    }
}

// ---------------------------------------------------------------------------
extern "C" void kernel_launch(void* const* d_in, const int* in_sizes, int n_in,
                              void* d_out, int out_size, void* d_ws, size_t ws_size,
                              hipStream_t stream)
{
    const float* node_embedding = (const float*)d_in[0];
    const float* node_pos       = (const float*)d_in[1];
    const float* grid_pos       = (const float*)d_in[2];
    const int*   edge_index     = (const int*)d_in[3];
    const float* ew1 = (const float*)d_in[4];
    const float* eb1 = (const float*)d_in[5];
    const float* ew2 = (const float*)d_in[6];
    const float* eb2 = (const float*)d_in[7];
    const float* mw1 = (const float*)d_in[8];
    const float* mb1 = (const float*)d_in[9];
    const float* mw2 = (const float*)d_in[10];
    const float* mb2 = (const float*)d_in[11];
    const float* uw1 = (const float*)d_in[12];
    const float* ub1 = (const float*)d_in[13];
    const float* uw2 = (const float*)d_in[14];
    const float* ub2 = (const float*)d_in[15];
    const float* c1a = (const float*)d_in[16];
    const float* c1b = (const float*)d_in[17];
    const float* c1s = (const float*)d_in[18];
    const float* c2a = (const float*)d_in[19];
    const float* c2b = (const float*)d_in[20];
    const float* c2s = (const float*)d_in[21];
    const float* c3a = (const float*)d_in[22];
    const float* c3b = (const float*)d_in[23];
    const float* c3s = (const float*)d_in[24];
    const float* fcw = (const float*)d_in[25];
    const float* fcb = (const float*)d_in[26];
    float* out = (float*)d_out;
    const int* edge_i = edge_index;   // row 0

    float* ws = (float*)d_ws;
    float* a_node = ws;                ws += 262144;
    float* g_vox  = ws;                ws += 262144;
    float* n_node = ws;                ws += 262144;
    float* W_mu   = ws;                ws += 4096;
    float* b_mu   = ws;                ws += 64;
    _Float16* wemt_h = (_Float16*)ws;  ws += 2048;
    _Float16* wemt_l = (_Float16*)ws;  ws += 2048;
    _Float16* x0h = (_Float16*)ws;     ws += 131072;
    _Float16* x0l = (_Float16*)ws;     ws += 131072;
    _Float16* t2h = (_Float16*)ws;     ws += 262144;
    _Float16* t2l = (_Float16*)ws;     ws += 262144;
    _Float16* x2h = (_Float16*)ws;     ws += 262144;
    _Float16* x2l = (_Float16*)ws;     ws += 262144;
    _Float16* t3h = (_Float16*)ws;     ws += 524288;
    _Float16* t3l = (_Float16*)ws;     ws += 524288;
    float* u2 = ws;                    ws += 524288;
    float* u3 = ws;                    ws += 1048576;
    float* slab = ws;                  ws += 5242880;
    float* poolPart = ws;              ws += 4096;
    _Float16* wh = (_Float16*)ws;      ws += 4585472;   // 9170944 f16
    _Float16* wl = (_Float16*)ws;      ws += 4585472;
    // aliases valid after edge_kernel (node tables dead):
    _Float16* t1h = (_Float16*)a_node;
    _Float16* t1l = (_Float16*)(a_node + 131072);
    float* u1 = g_vox;
    _Float16* x1h = (_Float16*)n_node;
    _Float16* x1l = (_Float16*)(n_node + 131072);

    _Float16* w1a_h = wh + 0;       _Float16* w1a_l = wl + 0;
    _Float16* w1b_h = wh + 110592;  _Float16* w1b_l = wl + 110592;
    _Float16* w1s_h = wh + 221184;  _Float16* w1s_l = wl + 221184;
    _Float16* w2a_h = wh + 733184;  _Float16* w2a_l = wl + 733184;
    _Float16* w2b_h = wh + 954368;  _Float16* w2b_l = wl + 954368;
    _Float16* w2s_h = wh + 1396736; _Float16* w2s_l = wl + 1396736;
    _Float16* w3a_h = wh + 2420736; _Float16* w3a_l = wl + 2420736;
    _Float16* w3b_h = wh + 3305472; _Float16* w3b_l = wl + 3305472;
    _Float16* w3s_h = wh + 5074944; _Float16* w3s_l = wl + 5074944;

    // ---- weight transpose + split ----
    hipLaunchKernelGGL((wsplit_k<27,1,2>),  dim3(64,2),  dim3(256), 0, stream, c1a, w1a_h, w1a_l, 64);
    hipLaunchKernelGGL((wsplit_k<27,1,2>),  dim3(64,2),  dim3(256), 0, stream, c1b, w1b_h, w1b_l, 64);
    hipLaunchKernelGGL((wsplit_k<125,1,2>), dim3(64,2),  dim3(256), 0, stream, c1s, w1s_h, w1s_l, 64);
    hipLaunchKernelGGL((wsplit_k<27,2,2>),  dim3(128,2), dim3(256), 0, stream, c2a, w2a_h, w2a_l, 64);
    hipLaunchKernelGGL((wsplit_k<27,2,4>),  dim3(128,4), dim3(256), 0, stream, c2b, w2b_h, w2b_l, 128);
    hipLaunchKernelGGL((wsplit_k<125,2,2>), dim3(128,2), dim3(256), 0, stream, c2s, w2s_h, w2s_l, 64);
    hipLaunchKernelGGL((wsplit_k<27,4,4>),  dim3(256,4), dim3(256), 0, stream, c3a, w3a_h, w3a_l, 128);
    hipLaunchKernelGGL((wsplit_k<27,4,8>),  dim3(256,8), dim3(256), 0, stream, c3b, w3b_h, w3b_l, 256);
    hipLaunchKernelGGL((wsplit_k<125,4,4>), dim3(256,4), dim3(256), 0, stream, c3s, w3s_h, w3s_l, 128);

    // ---- MPNN ----
    hipLaunchKernelGGL(prep_w_k, dim3(64), dim3(64), 0, stream,
                       ew2, mw1, mw2, uw1, mb2, ub1, W_mu, b_mu, wemt_h, wemt_l);
    hipLaunchKernelGGL(prep_nodes_k, dim3(4096), dim3(64), 0, stream,
                       node_embedding, node_pos, grid_pos, ew1, eb1, mw1, mb1, eb2,
                       a_node, g_vox, n_node);
    hipLaunchKernelGGL(edge_kernel, dim3(4096), dim3(256), 0, stream,
                       edge_i, a_node, g_vox, n_node, wemt_h, wemt_l,
                       W_mu, b_mu, uw2, ub2, x0h, x0l);

    // ---- ResNet3D ----
    // Block 1: 64 -> 64  (ci-split 2: S = 2*KK slabs)
    hipLaunchKernelGGL((conv_mfma_k<3,64,1,2>), dim3(16,1,6), dim3(256), 0, stream, x0h, x0l, w1a_h, w1a_l, slab);
    hipLaunchKernelGGL((reduce_k<6,1,1>), dim3(16,8), dim3(256), 0, stream, slab, (const float*)nullptr, (float*)nullptr, t1h, t1l, 64);
    hipLaunchKernelGGL((conv_mfma_k<3,64,1,2>), dim3(16,1,6), dim3(256), 0, stream, t1h, t1l, w1b_h, w1b_l, slab);
    hipLaunchKernelGGL((reduce_k<6,2,0>), dim3(16,8), dim3(256), 0, stream, slab, (const float*)nullptr, u1, (_Float16*)nullptr, (_Float16*)nullptr, 64);
    hipLaunchKernelGGL((conv_mfma_k<5,64,1,2>), dim3(16,1,10), dim3(256), 0, stream, x0h, x0l, w1s_h, w1s_l, slab);
    hipLaunchKernelGGL((reduce_k<10,3,1>), dim3(16,8), dim3(256), 0, stream, slab, u1, (float*)nullptr, x1h, x1l, 64);
    // Block 2: 64 -> 128
    hipLaunchKernelGGL((conv_mfma_k<3,64,2,2>), dim3(16,2,6), dim3(256), 0, stream, x1h, x1l, w2a_h, w2a_l, slab);
    hipLaunchKernelGGL((reduce_k<6,1,1>), dim3(16,16), dim3(256), 0, stream, slab, (const float*)nullptr, (float*)nullptr, t2h, t2l, 128);
    hipLaunchKernelGGL((conv_mfma_k<3,128,2,2>), dim3(16,2,6), dim3(256), 0, stream, t2h, t2l, w2b_h, w2b_l, slab);
    hipLaunchKernelGGL((reduce_k<6,2,0>), dim3(16,16), dim3(256), 0, stream, slab, (const float*)nullptr, u2, (_Float16*)nullptr, (_Float16*)nullptr, 128);
    hipLaunchKernelGGL((conv_mfma_k<5,64,2,2>), dim3(16,2,10), dim3(256), 0, stream, x1h, x1l, w2s_h, w2s_l, slab);
    hipLaunchKernelGGL((reduce_k<10,3,1>), dim3(16,16), dim3(256), 0, stream, slab, u2, (float*)nullptr, x2h, x2l, 128);
    // Block 3: 128 -> 256  (no ci-split: slab budget)
    hipLaunchKernelGGL((conv_mfma_k<3,128,4,1>), dim3(16,4,3), dim3(256), 0, stream, x2h, x2l, w3a_h, w3a_l, slab);
    hipLaunchKernelGGL((reduce_k<3,1,1>), dim3(16,32), dim3(256), 0, stream, slab, (const float*)nullptr, (float*)nullptr, t3h, t3l, 256);
    hipLaunchKernelGGL((conv_mfma_k<3,256,4,1>), dim3(16,4,3), dim3(256), 0, stream, t3h, t3l, w3b_h, w3b_l, slab);
    hipLaunchKernelGGL((reduce_k<3,2,0>), dim3(16,32), dim3(256), 0, stream, slab, (const float*)nullptr, u3, (_Float16*)nullptr, (_Float16*)nullptr, 256);
    hipLaunchKernelGGL((conv_mfma_k<5,128,4,1>), dim3(16,4,5), dim3(256), 0, stream, x2h, x2l, w3s_h, w3s_l, slab);
    hipLaunchKernelGGL((reduce_k<5,3,2>), dim3(16,32), dim3(256), 0, stream, slab, u3, poolPart, (_Float16*)nullptr, (_Float16*)nullptr, 256);

    hipLaunchKernelGGL(fc_k, dim3(1), dim3(256), 0, stream, poolPart, fcw, fcb, out);

    (void)in_sizes; (void)n_in; (void)out_size; (void)ws_size;
}